// Round 1
// 187.952 us; speedup vs baseline: 1.0165x; 1.0165x over previous
//
#include <hip/hip_runtime.h>

#define PI2 6.28318530717958647692f

// D = 10000 = 100 x 100; F = 5001; signals: 128 pos + 10 atom + 1 closure = 139
#define NSIG 139
#define FS   5120      // spectrum row stride (float2)

// ---------------- fused forward (f1+f2), Hermitian-paired, LDS-resident ----------------
__global__ __launch_bounds__(256) void k_fwd(
                     const float* __restrict__ atom, const float* __restrict__ pos,
                     const float* __restrict__ clo, float2* __restrict__ spec) {
  __shared__ float xs[5000];    // phase1: 50 x-rows; phase3: B rows (stride 200 floats)
  unsigned sig = blockIdx.x, q = blockIdx.y;
  unsigned k1base = q * 10u;
  unsigned nk1 = (k1base + 10u <= 51u) ? 10u : (51u - k1base);   // q=5 -> 1 (k1=50)
  const float* xb = (sig < 128u) ? (pos + sig * 10000u)
                   : ((sig < 138u) ? (atom + (sig - 128u) * 10000u) : clo);
  int tid = threadIdx.x;
  unsigned ntile1 = nk1 * 25u;
  unsigned k1l = tid / 25u, n2 = (tid % 25u) * 4u;
  bool have = (unsigned)tid < ntile1;
  unsigned k1 = k1base + k1l;
  float cth, sth;
  __sincosf(PI2 * (float)k1 * 0.01f, &sth, &cth);
  float c = 1.0f, s = 0.0f;
  float ar[4] = {}, as[4] = {};

  for (int h = 0; h < 2; ++h) {
    for (int i = tid; i < 1250; i += 256)
      *(float4*)(xs + 4 * i) = *(const float4*)(xb + h * 5000 + 4 * i);
    __syncthreads();
    if (have) {
#pragma unroll 5
      for (int n1l = 0; n1l < 50; ++n1l) {
        const float4 xv = *(const float4*)(xs + n1l * 100 + n2);
        ar[0] += xv.x * c; as[0] += xv.x * s;
        ar[1] += xv.y * c; as[1] += xv.y * s;
        ar[2] += xv.z * c; as[2] += xv.z * s;
        ar[3] += xv.w * c; as[3] += xv.w * s;
        float cn = c * cth - s * sth;
        float sn = s * cth + c * sth;
        c = cn; s = sn;
      }
    }
    __syncthreads();
  }

  if (have) {
    unsigned rb = (100u - k1) % 100u;
    float resA[8], resB[8];
#pragma unroll
    for (int j = 0; j < 4; ++j) {
      float swA, cwA, swB, cwB;
      __sincosf(PI2 * (float)((n2 + j) * k1) * 1e-4f, &swA, &cwA);
      __sincosf(PI2 * (float)((n2 + j) * rb) * 1e-4f, &swB, &cwB);
      resA[2 * j + 0] = ar[j] * cwA - as[j] * swA;
      resA[2 * j + 1] = -(as[j] * cwA + ar[j] * swA);
      resB[2 * j + 0] = ar[j] * cwB + as[j] * swB;
      resB[2 * j + 1] = as[j] * cwB - ar[j] * swB;
    }
    float* pA = xs + k1l * 200u + n2 * 2u;
    float* pB = xs + (nk1 + k1l) * 200u + n2 * 2u;
    *(float4*)(pA + 0) = make_float4(resA[0], resA[1], resA[2], resA[3]);
    *(float4*)(pA + 4) = make_float4(resA[4], resA[5], resA[6], resA[7]);
    *(float4*)(pB + 0) = make_float4(resB[0], resB[1], resB[2], resB[3]);
    *(float4*)(pB + 4) = make_float4(resB[4], resB[5], resB[6], resB[7]);
  }
  __syncthreads();

  unsigned nrow = 2u * nk1;
  unsigned ntile3 = nrow * 26u;
  for (unsigned t = tid; t < ntile3; t += 256u) {
    unsigned lr = t / 26u, k2 = (t % 26u) * 2u;
    unsigned gk1 = (lr < nk1) ? (k1base + lr) : ((100u - (k1base + (lr - nk1))) % 100u);
    const float* brow = xs + lr * 200u;
    float cthA, sthA, cthB, sthB;
    __sincosf(PI2 * (float)k2 * 0.01f, &sthA, &cthA);
    __sincosf(PI2 * (float)(k2 + 1) * 0.01f, &sthB, &cthB);
    float cA = 1.0f, sA = 0.0f, cB = 1.0f, sB = 0.0f;
    float reA = 0.f, imA = 0.f, reB = 0.f, imB = 0.f;
#pragma unroll 4
    for (int n2i = 0; n2i < 100; n2i += 2) {
      const float4 b0 = *(const float4*)(brow + 2 * n2i);
      reA += b0.x * cA + b0.y * sA;  imA += b0.y * cA - b0.x * sA;
      reB += b0.x * cB + b0.y * sB;  imB += b0.y * cB - b0.x * sB;
      float cA1 = cA * cthA - sA * sthA, sA1 = sA * cthA + cA * sthA;
      float cB1 = cB * cthB - sB * sthB, sB1 = sB * cthB + cB * sthB;
      reA += b0.z * cA1 + b0.w * sA1;  imA += b0.w * cA1 - b0.z * sA1;
      reB += b0.z * cB1 + b0.w * sB1;  imB += b0.w * cB1 - b0.z * sB1;
      cA = cA1 * cthA - sA1 * sthA; sA = sA1 * cthA + cA1 * sthA;
      cB = cB1 * cthB - sB1 * sthB; sB = sB1 * cthB + cB1 * sthB;
    }
    unsigned kA = gk1 + 100u * k2;
    unsigned kB = gk1 + 100u * (k2 + 1);
    if (kA <= 5000u) spec[sig * FS + kA] = make_float2(reA, imA);
    if (kB <= 5000u) spec[sig * FS + kB] = make_float2(reB, imB);
  }
}

// ---------------- mix: b-tile 4, k-chunk 128, 2-way s-split; grid (40,16) = 640 blocks ----------------
// Per-molecule spec traffic 4x lower than b-tile-2/k-256 version; same occupancy.
__global__ __launch_bounds__(256) void k_mix(const float2* __restrict__ spec,
                      const float* __restrict__ tmask, const float* __restrict__ rmask,
                      const int* __restrict__ aidx, const int* __restrict__ rpos,
                      float2* __restrict__ G) {
  __shared__ float2 FaS[10][128];
  __shared__ float2 FcS[128];
  __shared__ float tmS[4][128];
  __shared__ int   aiS[4][128];
  __shared__ float rmS[4][8];
  __shared__ int   rpS[4][8][2];
  __shared__ float2 red[2][4][128];
  int tid = threadIdx.x;
  int kl = tid & 127, half = tid >> 7;
  int k = blockIdx.x * 128 + kl;
  int kc = k > 5000 ? 5000 : k;
  int b0 = blockIdx.y * 4;
  for (int i = tid; i < 10 * 128; i += 256) {
    int a = i >> 7, kk = i & 127;
    int kg = blockIdx.x * 128 + kk; if (kg > 5000) kg = 5000;
    FaS[a][kk] = spec[(128 + a) * FS + kg];
  }
  if (tid < 128) FcS[tid] = spec[138 * FS + kc];
  for (int i = tid; i < 4 * 128; i += 256) {
    int bb = i >> 7, ss = i & 127;
    tmS[bb][ss] = tmask[(b0 + bb) * 128 + ss];
    aiS[bb][ss] = aidx[(b0 + bb) * 128 + ss];
  }
  if (tid < 32) {
    int bb = tid >> 3, rr = tid & 7;
    rmS[bb][rr] = rmask[(b0 + bb) * 8 + rr];
    rpS[bb][rr][0] = rpos[((b0 + bb) * 8 + rr) * 2 + 0];
    rpS[bb][rr][1] = rpos[((b0 + bb) * 8 + rr) * 2 + 1];
  }
  __syncthreads();
  float fr[4] = {}, fi[4] = {};
  int sbase = half * 64;
#pragma unroll 8
  for (int si = 0; si < 64; ++si) {
    int s = sbase + si;
    float2 fp = spec[s * FS + kc];
#pragma unroll
    for (int b = 0; b < 4; ++b) {
      int a = aiS[b][s];
      float tm = tmS[b][s];
      float2 fa = FaS[a][kl];
      fr[b] += tm * (fa.x * fp.x - fa.y * fp.y);
      fi[b] += tm * (fa.x * fp.y + fa.y * fp.x);
    }
  }
  float2 fc = FcS[kl];
#pragma unroll
  for (int rr = 0; rr < 4; ++rr) {
    int r = half * 4 + rr;
#pragma unroll
    for (int b = 0; b < 4; ++b) {
      int p0 = rpS[b][r][0], p1 = rpS[b][r][1];
      float rm = rmS[b][r];
      float2 f0 = spec[p0 * FS + kc];
      float2 f1 = spec[p1 * FS + kc];
      float tr = f0.x * f1.x - f0.y * f1.y;
      float ti = f0.x * f1.y + f0.y * f1.x;
      fr[b] += rm * (tr * fc.x - ti * fc.y);
      fi[b] += rm * (tr * fc.y + ti * fc.x);
    }
  }
#pragma unroll
  for (int b = 0; b < 4; ++b) red[half][b][kl] = make_float2(fr[b], fi[b]);
  __syncthreads();
  if (k <= 5000) {
#pragma unroll
    for (int j = 0; j < 2; ++j) {
      int b = half + 2 * j;
      float R = red[0][b][kl].x + red[1][b][kl].x;
      float I = red[0][b][kl].y + red[1][b][kl].y;
      if (k == 0 || k == 5000) I = 0.0f;   // exact Hermitian guard
      G[(size_t)(b0 + b) * 10000 + k] = make_float2(R, I);
      if (k >= 1 && k <= 4999)
        G[(size_t)(b0 + b) * 10000 + (10000 - k)] = make_float2(R, -I);
    }
  }
}

// ---------------- inverse stage 1: tile 1 m1 x 2 n2, quarter-staged G (10.4 KB) ----------------
__global__ __launch_bounds__(256) void k_i1(const float2* __restrict__ G,
                                            float2* __restrict__ Bi) {
  __shared__ float gs[2600];    // 25 G-rows x 52 complex (104 floats/row)
  unsigned sig = blockIdx.x;
  const float* gp = (const float*)(G + sig * 10000u);
  int tid = threadIdx.x;
  unsigned t = blockIdx.y * 256u + tid;
  bool have = t < 2600u;
  unsigned m1 = t / 26u, n2 = (t % 26u) * 2u;
  float cth, sth;
  __sincosf(PI2 * (float)m1 * 0.01f, &sth, &cth);
  float reA = 0.f, imA = 0.f, reB = 0.f, imB = 0.f;

  for (int h = 0; h < 4; ++h) {
    if (h) __syncthreads();
    for (int i = tid; i < 650; i += 256) {
      int row = i / 26, c4 = i % 26;
      *(float4*)(gs + row * 104 + c4 * 4) =
          *(const float4*)(gp + (h * 25 + row) * 200 + c4 * 4);
    }
    __syncthreads();
    if (have) {
      unsigned ph = (m1 * (unsigned)h) & 3u;
      float c = (ph == 0u) ? 1.0f : (ph == 2u) ? -1.0f : 0.0f;
      float s = (ph == 1u) ? 1.0f : (ph == 3u) ? -1.0f : 0.0f;
#pragma unroll 5
      for (int n1l = 0; n1l < 25; ++n1l) {
        const float4 gv = *(const float4*)(gs + n1l * 104 + n2 * 2);
        reA += gv.x * c - gv.y * s;  imA += gv.y * c + gv.x * s;
        reB += gv.z * c - gv.w * s;  imB += gv.w * c + gv.z * s;
        float cn = c * cth - s * sth;
        float sn = s * cth + c * sth;
        c = cn; s = sn;
      }
    }
  }
  if (have) {
    float w0 = (n2 == 0u || n2 == 50u) ? 0.5f : 1.0f;
    float w1 = (n2 == 50u) ? 0.0f : 1.0f;   // col 51 unused
    float sw0, cw0, sw1, cw1;
    __sincosf(PI2 * (float)(n2 * m1) * 1e-4f, &sw0, &cw0);
    __sincosf(PI2 * (float)((n2 + 1u) * m1) * 1e-4f, &sw1, &cw1);
    float4 outv;
    outv.x = (reA * cw0 - imA * sw0) * w0;
    outv.y = (imA * cw0 + reA * sw0) * w0;
    outv.z = (reB * cw1 - imB * sw1) * w1;
    outv.w = (imB * cw1 + reB * sw1) * w1;
    *(float4*)((float*)Bi + (sig * 5200u + m1 * 52u + n2) * 2) = outv;
  }
}

// ---------------- inverse stage 2: quarter-staged Bi (10.4 KB), tile 1 m1 x 2 m2 ----------------
__global__ __launch_bounds__(256) void k_i2(const float2* __restrict__ Bi,
                                            float* __restrict__ mol) {
  __shared__ float bs[2600];    // 25 Bi-rows x 52 complex
  unsigned sig = blockIdx.x, q = blockIdx.y;
  int tid = threadIdx.x;
  const float* bp = (const float*)Bi + sig * 10400u + q * 2600u;   // contiguous quarter
  for (int i = tid; i < 650; i += 256)
    *(float4*)(bs + 4 * i) = *(const float4*)(bp + 4 * i);
  __syncthreads();
  unsigned t = blockIdx.z * 256u + tid;
  if (t >= 1250u) return;
  unsigned m1l = t / 50u;              // 0..24
  unsigned m2 = (t % 50u) * 2u;        // fastest
  const float* b0 = bs + m1l * 104u;
  float cthA, sthA, cthB, sthB;
  __sincosf(PI2 * (float)m2 * 0.01f, &sthA, &cthA);
  __sincosf(PI2 * (float)(m2 + 1u) * 0.01f, &sthB, &cthB);
  float cA = 1.0f, sA = 0.0f, cB = 1.0f, sB = 0.0f;
  float r0 = 0.f, r1 = 0.f;
#pragma unroll 4
  for (int jj = 0; jj < 26; ++jj) {
    int n2i = 2 * jj;
    const float4 v0 = *(const float4*)(b0 + 2 * n2i);
    r0 += v0.x * cA - v0.y * sA;
    r1 += v0.x * cB - v0.y * sB;
    float cA1 = cA * cthA - sA * sthA, sA1 = sA * cthA + cA * sthA;
    float cB1 = cB * cthB - sB * sthB, sB1 = sB * cthB + cB * sthB;
    r0 += v0.z * cA1 - v0.w * sA1;
    r1 += v0.z * cB1 - v0.w * sB1;
    cA = cA1 * cthA - sA1 * sthA; sA = sA1 * cthA + cA1 * sthA;
    cB = cB1 * cthB - sB1 * sthB; sB = sB1 * cthB + cB1 * sthB;
  }
  unsigned m1 = q * 25u + m1l;
  mol[sig * 10000u + m1 + 100u * m2] = r0 * 2e-4f;
  mol[sig * 10000u + m1 + 100u * (m2 + 1u)] = r1 * 2e-4f;
}

// ---------------- projection: 250 chunks of 40, 512-thread blocks (2 waves/SIMD) ----------------
__global__ __launch_bounds__(512) void k_proj(const float* __restrict__ mol,
                                              const float* __restrict__ W,
                                              float* __restrict__ part) {
  __shared__ float molS[40 * 64];
  int tid = threadIdx.x;
  int d0 = blockIdx.x * 40;
  for (int i = tid; i < 40 * 64; i += 512)
    molS[i] = mol[(size_t)(i & 63) * 10000 + d0 + (i >> 6)];
  __syncthreads();
  int p0 = (tid & 127) * 2;
  int bh = (tid >> 7) * 16;
  float acc[2][16] = {};
  const float* w0 = W + (size_t)(p0 + 0) * 10000 + d0;
  const float* w1 = W + (size_t)(p0 + 1) * 10000 + d0;
#pragma unroll 4
  for (int dl = 0; dl < 40; ++dl) {
    const float wv0 = w0[dl], wv1 = w1[dl];
    const float4* m4 = (const float4*)(molS + dl * 64 + bh);
#pragma unroll
    for (int q = 0; q < 4; ++q) {
      float4 mv = m4[q];
      acc[0][4 * q + 0] += wv0 * mv.x;  acc[1][4 * q + 0] += wv1 * mv.x;
      acc[0][4 * q + 1] += wv0 * mv.y;  acc[1][4 * q + 1] += wv1 * mv.y;
      acc[0][4 * q + 2] += wv0 * mv.z;  acc[1][4 * q + 2] += wv1 * mv.z;
      acc[0][4 * q + 3] += wv0 * mv.w;  acc[1][4 * q + 3] += wv1 * mv.w;
    }
  }
#pragma unroll
  for (int b = 0; b < 16; ++b)
    *(float2*)(part + (size_t)blockIdx.x * 16384 + (bh + b) * 256 + p0) =
        make_float2(acc[0][b], acc[1][b]);
}

// ---------------- reduce partials + bias: grid (64 b, 4 p-quarters), 256 threads, 4 chunk-groups ----------------
__global__ __launch_bounds__(256) void k_red(const float* __restrict__ part,
                                             const float* __restrict__ bias,
                                             float* __restrict__ out) {
  __shared__ float red[4][64];
  int tid = threadIdx.x;
  int pl = tid & 63, cg = tid >> 6;
  int b = blockIdx.x;
  int p = blockIdx.y * 64 + pl;
  float acc = 0.0f;
#pragma unroll 8
  for (int ch = cg; ch < 250; ch += 4)
    acc += part[(size_t)ch * 16384 + b * 256 + p];
  red[cg][pl] = acc;
  __syncthreads();
  if (tid < 64)
    out[b * 256 + p] = red[0][pl] + red[1][pl] + red[2][pl] + red[3][pl] + bias[p];
}

extern "C" void kernel_launch(void* const* d_in, const int* in_sizes, int n_in,
                              void* d_out, int out_size, void* d_ws, size_t ws_size,
                              hipStream_t stream) {
  const float* atom  = (const float*)d_in[0];   // [10,10000]
  const float* pos   = (const float*)d_in[1];   // [128,10000]
  const float* clo   = (const float*)d_in[2];   // [10000]
  const float* W     = (const float*)d_in[3];   // [256,10000]
  const float* bias  = (const float*)d_in[4];   // [256]
  const float* tmask = (const float*)d_in[5];   // [64,128]
  const float* rmask = (const float*)d_in[6];   // [64,8]
  const int*   aidx  = (const int*)d_in[7];     // [64,128]
  const int*   rpos  = (const int*)d_in[8];     // [64,8,2]
  float* out = (float*)d_out;                   // [64,256]

  char* ws = (char*)d_ws;
  size_t off = 0;
  auto alloc = [&](size_t n) { off = (off + 255) & ~(size_t)255; size_t o = off; off += n; return o; };
  char* regA   = ws + alloc(16777216);          // Bi (2.66MB) / partials (16.4MB)
  float2* Bi   = (float2*)regA;                 // i1/i2 use Bi before proj writes part
  float*  part = (float*)regA;
  float2* spec = (float2*)(ws + alloc((size_t)NSIG * FS * 8));
  float2* G    = (float2*)(ws + alloc((size_t)64 * 10000 * 8));
  float*  mol  = (float*)(ws + alloc((size_t)64 * 10000 * 4));

  k_fwd<<<dim3(NSIG, 6), dim3(256), 0, stream>>>(atom, pos, clo, spec);
  k_mix<<<dim3(40, 16), dim3(256), 0, stream>>>(spec, tmask, rmask, aidx, rpos, G);
  k_i1<<<dim3(64, 11), dim3(256), 0, stream>>>(G, Bi);
  k_i2<<<dim3(64, 4, 5), dim3(256), 0, stream>>>(Bi, mol);
  k_proj<<<dim3(250), dim3(512), 0, stream>>>(mol, W, part);
  k_red<<<dim3(64, 4), dim3(256), 0, stream>>>(part, bias, out);
}

// Round 2
// 185.369 us; speedup vs baseline: 1.0307x; 1.0139x over previous
//
#include <hip/hip_runtime.h>

#define PI2 6.28318530717958647692f

// D = 10000 = 100 x 100; F = 5001; signals: 128 pos + 10 atom + 1 closure = 139
#define NSIG 139
#define FS   5120      // spectrum row stride (float2)

// ---------------- fused forward (f1+f2), Hermitian-paired ----------------
// Phase 1 reads x directly from global (L1-stream, no staging barriers / LDS conflicts).
// LDS only carries the phase2 -> phase3 intermediate (nrow x 200 floats).
__global__ __launch_bounds__(256) void k_fwd(
                     const float* __restrict__ atom, const float* __restrict__ pos,
                     const float* __restrict__ clo, float2* __restrict__ spec) {
  __shared__ float xs[4000];    // phase3 buffer: up to 20 rows x 200 floats
  unsigned sig = blockIdx.x, q = blockIdx.y;
  unsigned k1base = q * 10u;
  unsigned nk1 = (k1base + 10u <= 51u) ? 10u : (51u - k1base);   // q=5 -> 1 (k1=50)
  const float* xb = (sig < 128u) ? (pos + sig * 10000u)
                   : ((sig < 138u) ? (atom + (sig - 128u) * 10000u) : clo);
  int tid = threadIdx.x;
  unsigned ntile1 = nk1 * 25u;
  unsigned k1l = tid / 25u, n2 = (tid % 25u) * 4u;
  bool have = (unsigned)tid < ntile1;
  unsigned k1 = k1base + k1l;
  float cth, sth;
  __sincosf(PI2 * (float)k1 * 0.01f, &sth, &cth);
  float c = 1.0f, s = 0.0f;
  float ar[4] = {}, as[4] = {};

  if (have) {
#pragma unroll 10
    for (int n1l = 0; n1l < 100; ++n1l) {
      const float4 xv = *(const float4*)(xb + n1l * 100 + n2);
      ar[0] += xv.x * c; as[0] += xv.x * s;
      ar[1] += xv.y * c; as[1] += xv.y * s;
      ar[2] += xv.z * c; as[2] += xv.z * s;
      ar[3] += xv.w * c; as[3] += xv.w * s;
      float cn = c * cth - s * sth;
      float sn = s * cth + c * sth;
      c = cn; s = sn;
    }
    unsigned rb = (100u - k1) % 100u;
    float resA[8], resB[8];
#pragma unroll
    for (int j = 0; j < 4; ++j) {
      float swA, cwA, swB, cwB;
      __sincosf(PI2 * (float)((n2 + j) * k1) * 1e-4f, &swA, &cwA);
      __sincosf(PI2 * (float)((n2 + j) * rb) * 1e-4f, &swB, &cwB);
      resA[2 * j + 0] = ar[j] * cwA - as[j] * swA;
      resA[2 * j + 1] = -(as[j] * cwA + ar[j] * swA);
      resB[2 * j + 0] = ar[j] * cwB + as[j] * swB;
      resB[2 * j + 1] = as[j] * cwB - ar[j] * swB;
    }
    float* pA = xs + k1l * 200u + n2 * 2u;
    float* pB = xs + (nk1 + k1l) * 200u + n2 * 2u;
    *(float4*)(pA + 0) = make_float4(resA[0], resA[1], resA[2], resA[3]);
    *(float4*)(pA + 4) = make_float4(resA[4], resA[5], resA[6], resA[7]);
    *(float4*)(pB + 0) = make_float4(resB[0], resB[1], resB[2], resB[3]);
    *(float4*)(pB + 4) = make_float4(resB[4], resB[5], resB[6], resB[7]);
  }
  __syncthreads();

  unsigned nrow = 2u * nk1;
  unsigned ntile3 = nrow * 26u;
  for (unsigned t = tid; t < ntile3; t += 256u) {
    unsigned lr = t / 26u, k2 = (t % 26u) * 2u;
    unsigned gk1 = (lr < nk1) ? (k1base + lr) : ((100u - (k1base + (lr - nk1))) % 100u);
    const float* brow = xs + lr * 200u;
    float cthA, sthA, cthB, sthB;
    __sincosf(PI2 * (float)k2 * 0.01f, &sthA, &cthA);
    __sincosf(PI2 * (float)(k2 + 1) * 0.01f, &sthB, &cthB);
    float cA = 1.0f, sA = 0.0f, cB = 1.0f, sB = 0.0f;
    float reA = 0.f, imA = 0.f, reB = 0.f, imB = 0.f;
#pragma unroll 4
    for (int n2i = 0; n2i < 100; n2i += 2) {
      const float4 b0 = *(const float4*)(brow + 2 * n2i);
      reA += b0.x * cA + b0.y * sA;  imA += b0.y * cA - b0.x * sA;
      reB += b0.x * cB + b0.y * sB;  imB += b0.y * cB - b0.x * sB;
      float cA1 = cA * cthA - sA * sthA, sA1 = sA * cthA + cA * sthA;
      float cB1 = cB * cthB - sB * sthB, sB1 = sB * cthB + cB * sthB;
      reA += b0.z * cA1 + b0.w * sA1;  imA += b0.w * cA1 - b0.z * sA1;
      reB += b0.z * cB1 + b0.w * sB1;  imB += b0.w * cB1 - b0.z * sB1;
      cA = cA1 * cthA - sA1 * sthA; sA = sA1 * cthA + cA1 * sthA;
      cB = cB1 * cthB - sB1 * sthB; sB = sB1 * cthB + cB1 * sthB;
    }
    unsigned kA = gk1 + 100u * k2;
    unsigned kB = gk1 + 100u * (k2 + 1);
    if (kA <= 5000u) spec[sig * FS + kA] = make_float2(reA, imA);
    if (kB <= 5000u) spec[sig * FS + kB] = make_float2(reB, imB);
  }
}

// ---------------- mix: b-tile 4, k-chunk 128, 2-way s-split; grid (40,16) = 640 blocks ----------------
__global__ __launch_bounds__(256) void k_mix(const float2* __restrict__ spec,
                      const float* __restrict__ tmask, const float* __restrict__ rmask,
                      const int* __restrict__ aidx, const int* __restrict__ rpos,
                      float2* __restrict__ G) {
  __shared__ float2 FaS[10][128];
  __shared__ float2 FcS[128];
  __shared__ float tmS[4][128];
  __shared__ int   aiS[4][128];
  __shared__ float rmS[4][8];
  __shared__ int   rpS[4][8][2];
  __shared__ float2 red[2][4][128];
  int tid = threadIdx.x;
  int kl = tid & 127, half = tid >> 7;
  int k = blockIdx.x * 128 + kl;
  int kc = k > 5000 ? 5000 : k;
  int b0 = blockIdx.y * 4;
  for (int i = tid; i < 10 * 128; i += 256) {
    int a = i >> 7, kk = i & 127;
    int kg = blockIdx.x * 128 + kk; if (kg > 5000) kg = 5000;
    FaS[a][kk] = spec[(128 + a) * FS + kg];
  }
  if (tid < 128) FcS[tid] = spec[138 * FS + kc];
  for (int i = tid; i < 4 * 128; i += 256) {
    int bb = i >> 7, ss = i & 127;
    tmS[bb][ss] = tmask[(b0 + bb) * 128 + ss];
    aiS[bb][ss] = aidx[(b0 + bb) * 128 + ss];
  }
  if (tid < 32) {
    int bb = tid >> 3, rr = tid & 7;
    rmS[bb][rr] = rmask[(b0 + bb) * 8 + rr];
    rpS[bb][rr][0] = rpos[((b0 + bb) * 8 + rr) * 2 + 0];
    rpS[bb][rr][1] = rpos[((b0 + bb) * 8 + rr) * 2 + 1];
  }
  __syncthreads();
  float fr[4] = {}, fi[4] = {};
  int sbase = half * 64;
#pragma unroll 8
  for (int si = 0; si < 64; ++si) {
    int s = sbase + si;
    float2 fp = spec[s * FS + kc];
#pragma unroll
    for (int b = 0; b < 4; ++b) {
      int a = aiS[b][s];
      float tm = tmS[b][s];
      float2 fa = FaS[a][kl];
      fr[b] += tm * (fa.x * fp.x - fa.y * fp.y);
      fi[b] += tm * (fa.x * fp.y + fa.y * fp.x);
    }
  }
  float2 fc = FcS[kl];
#pragma unroll
  for (int rr = 0; rr < 4; ++rr) {
    int r = half * 4 + rr;
#pragma unroll
    for (int b = 0; b < 4; ++b) {
      int p0 = rpS[b][r][0], p1 = rpS[b][r][1];
      float rm = rmS[b][r];
      float2 f0 = spec[p0 * FS + kc];
      float2 f1 = spec[p1 * FS + kc];
      float tr = f0.x * f1.x - f0.y * f1.y;
      float ti = f0.x * f1.y + f0.y * f1.x;
      fr[b] += rm * (tr * fc.x - ti * fc.y);
      fi[b] += rm * (tr * fc.y + ti * fc.x);
    }
  }
#pragma unroll
  for (int b = 0; b < 4; ++b) red[half][b][kl] = make_float2(fr[b], fi[b]);
  __syncthreads();
  if (k <= 5000) {
#pragma unroll
    for (int j = 0; j < 2; ++j) {
      int b = half + 2 * j;
      float R = red[0][b][kl].x + red[1][b][kl].x;
      float I = red[0][b][kl].y + red[1][b][kl].y;
      if (k == 0 || k == 5000) I = 0.0f;   // exact Hermitian guard
      G[(size_t)(b0 + b) * 10000 + k] = make_float2(R, I);
      if (k >= 1 && k <= 4999)
        G[(size_t)(b0 + b) * 10000 + (10000 - k)] = make_float2(R, -I);
    }
  }
}

// ---------------- inverse stage 1: direct-global G reads, barrier-free ----------------
// Same exact quarter phase re-init as staged version (numerically identical);
// wave reads are a contiguous 416 B span per row -> coalesced, L1/L2-resident.
__global__ __launch_bounds__(256) void k_i1(const float2* __restrict__ G,
                                            float2* __restrict__ Bi) {
  unsigned sig = blockIdx.x;
  const float* gp = (const float*)(G + sig * 10000u);
  int tid = threadIdx.x;
  unsigned t = blockIdx.y * 256u + tid;
  if (t >= 2600u) return;
  unsigned m1 = t / 26u, n2 = (t % 26u) * 2u;
  float cth, sth;
  __sincosf(PI2 * (float)m1 * 0.01f, &sth, &cth);
  float reA = 0.f, imA = 0.f, reB = 0.f, imB = 0.f;

  for (int h = 0; h < 4; ++h) {
    // start phase e^{+i*pi*m1*h/2}: exact by (m1*h) mod 4
    unsigned ph = (m1 * (unsigned)h) & 3u;
    float c = (ph == 0u) ? 1.0f : (ph == 2u) ? -1.0f : 0.0f;
    float s = (ph == 1u) ? 1.0f : (ph == 3u) ? -1.0f : 0.0f;
#pragma unroll 5
    for (int n1l = 0; n1l < 25; ++n1l) {
      const float4 gv = *(const float4*)(gp + (h * 25 + n1l) * 200 + n2 * 2);
      reA += gv.x * c - gv.y * s;  imA += gv.y * c + gv.x * s;
      reB += gv.z * c - gv.w * s;  imB += gv.w * c + gv.z * s;
      float cn = c * cth - s * sth;
      float sn = s * cth + c * sth;
      c = cn; s = sn;
    }
  }
  float w0 = (n2 == 0u || n2 == 50u) ? 0.5f : 1.0f;
  float w1 = (n2 == 50u) ? 0.0f : 1.0f;   // col 51 unused
  float sw0, cw0, sw1, cw1;
  __sincosf(PI2 * (float)(n2 * m1) * 1e-4f, &sw0, &cw0);
  __sincosf(PI2 * (float)((n2 + 1u) * m1) * 1e-4f, &sw1, &cw1);
  float4 outv;
  outv.x = (reA * cw0 - imA * sw0) * w0;
  outv.y = (imA * cw0 + reA * sw0) * w0;
  outv.z = (reB * cw1 - imB * sw1) * w1;
  outv.w = (imB * cw1 + reB * sw1) * w1;
  *(float4*)((float*)Bi + (sig * 5200u + m1 * 52u + n2) * 2) = outv;
}

// ---------------- inverse stage 2: direct-global Bi reads (wave-broadcast, L1-hit) ----------------
__global__ __launch_bounds__(256) void k_i2(const float2* __restrict__ Bi,
                                            float* __restrict__ mol) {
  unsigned sig = blockIdx.x, q = blockIdx.y;
  int tid = threadIdx.x;
  unsigned t = blockIdx.z * 256u + tid;
  if (t >= 1250u) return;
  unsigned m1l = t / 50u;              // 0..24
  unsigned m2 = (t % 50u) * 2u;        // fastest
  const float* b0 = (const float*)Bi + sig * 10400u + q * 2600u + m1l * 104u;
  float cthA, sthA, cthB, sthB;
  __sincosf(PI2 * (float)m2 * 0.01f, &sthA, &cthA);
  __sincosf(PI2 * (float)(m2 + 1u) * 0.01f, &sthB, &cthB);
  float cA = 1.0f, sA = 0.0f, cB = 1.0f, sB = 0.0f;
  float r0 = 0.f, r1 = 0.f;
#pragma unroll 4
  for (int jj = 0; jj < 26; ++jj) {
    int n2i = 2 * jj;
    const float4 v0 = *(const float4*)(b0 + 2 * n2i);
    r0 += v0.x * cA - v0.y * sA;
    r1 += v0.x * cB - v0.y * sB;
    float cA1 = cA * cthA - sA * sthA, sA1 = sA * cthA + cA * sthA;
    float cB1 = cB * cthB - sB * sthB, sB1 = sB * cthB + cB * sthB;
    r0 += v0.z * cA1 - v0.w * sA1;
    r1 += v0.z * cB1 - v0.w * sB1;
    cA = cA1 * cthA - sA1 * sthA; sA = sA1 * cthA + cA1 * sthA;
    cB = cB1 * cthB - sB1 * sthB; sB = sB1 * cthB + cB1 * sthB;
  }
  unsigned m1 = q * 25u + m1l;
  mol[sig * 10000u + m1 + 100u * m2] = r0 * 2e-4f;
  mol[sig * 10000u + m1 + 100u * (m2 + 1u)] = r1 * 2e-4f;
}

// ---------------- projection: LDS-transposed W + mol (coalesced global, conflict-light LDS) ----------------
// Old version: 80 scalar W loads/thread with 64 distinct cachelines per wave-load
// (rows 40 KB apart) -> TA serialization. Now W staged transposed [40][258] via
// coalesced 40-float runs; compute reads are stride-2 float2 (4-way, 1.58x) and
// molS reads are wave-broadcast.
__global__ __launch_bounds__(512) void k_proj(const float* __restrict__ mol,
                                              const float* __restrict__ W,
                                              float* __restrict__ part) {
  __shared__ float molS[40 * 66];      // [dl][b] padded
  __shared__ float WS[40][258];        // [dl][p] padded
  int tid = threadIdx.x;
  int d0 = blockIdx.x * 40;
  for (int i = tid; i < 40 * 64; i += 512) {
    int b = i / 40, dl = i % 40;
    molS[dl * 66 + b] = mol[(size_t)b * 10000 + d0 + dl];
  }
  for (int i = tid; i < 40 * 256; i += 512) {
    int p = i / 40, dl = i % 40;
    WS[dl][p] = W[(size_t)p * 10000 + d0 + dl];
  }
  __syncthreads();
  int p0 = (tid & 127) * 2;
  int bh = (tid >> 7) * 16;
  float acc[2][16] = {};
#pragma unroll 4
  for (int dl = 0; dl < 40; ++dl) {
    const float2 wv = *(const float2*)(&WS[dl][p0]);
    const float2* m2p = (const float2*)(molS + dl * 66 + bh);
#pragma unroll
    for (int qq = 0; qq < 8; ++qq) {
      float2 mv = m2p[qq];
      acc[0][2 * qq + 0] += wv.x * mv.x;  acc[1][2 * qq + 0] += wv.y * mv.x;
      acc[0][2 * qq + 1] += wv.x * mv.y;  acc[1][2 * qq + 1] += wv.y * mv.y;
    }
  }
#pragma unroll
  for (int b = 0; b < 16; ++b)
    *(float2*)(part + (size_t)blockIdx.x * 16384 + (bh + b) * 256 + p0) =
        make_float2(acc[0][b], acc[1][b]);
}

// ---------------- reduce partials + bias: grid (64 b, 4 p-quarters), 256 threads, 4 chunk-groups ----------------
__global__ __launch_bounds__(256) void k_red(const float* __restrict__ part,
                                             const float* __restrict__ bias,
                                             float* __restrict__ out) {
  __shared__ float red[4][64];
  int tid = threadIdx.x;
  int pl = tid & 63, cg = tid >> 6;
  int b = blockIdx.x;
  int p = blockIdx.y * 64 + pl;
  float acc = 0.0f;
#pragma unroll 8
  for (int ch = cg; ch < 250; ch += 4)
    acc += part[(size_t)ch * 16384 + b * 256 + p];
  red[cg][pl] = acc;
  __syncthreads();
  if (tid < 64)
    out[b * 256 + p] = red[0][pl] + red[1][pl] + red[2][pl] + red[3][pl] + bias[p];
}

extern "C" void kernel_launch(void* const* d_in, const int* in_sizes, int n_in,
                              void* d_out, int out_size, void* d_ws, size_t ws_size,
                              hipStream_t stream) {
  const float* atom  = (const float*)d_in[0];   // [10,10000]
  const float* pos   = (const float*)d_in[1];   // [128,10000]
  const float* clo   = (const float*)d_in[2];   // [10000]
  const float* W     = (const float*)d_in[3];   // [256,10000]
  const float* bias  = (const float*)d_in[4];   // [256]
  const float* tmask = (const float*)d_in[5];   // [64,128]
  const float* rmask = (const float*)d_in[6];   // [64,8]
  const int*   aidx  = (const int*)d_in[7];     // [64,128]
  const int*   rpos  = (const int*)d_in[8];     // [64,8,2]
  float* out = (float*)d_out;                   // [64,256]

  char* ws = (char*)d_ws;
  size_t off = 0;
  auto alloc = [&](size_t n) { off = (off + 255) & ~(size_t)255; size_t o = off; off += n; return o; };
  char* regA   = ws + alloc(16777216);          // Bi (2.66MB) / partials (16.4MB)
  float2* Bi   = (float2*)regA;                 // i1/i2 use Bi before proj writes part
  float*  part = (float*)regA;
  float2* spec = (float2*)(ws + alloc((size_t)NSIG * FS * 8));
  float2* G    = (float2*)(ws + alloc((size_t)64 * 10000 * 8));
  float*  mol  = (float*)(ws + alloc((size_t)64 * 10000 * 4));

  k_fwd<<<dim3(NSIG, 6), dim3(256), 0, stream>>>(atom, pos, clo, spec);
  k_mix<<<dim3(40, 16), dim3(256), 0, stream>>>(spec, tmask, rmask, aidx, rpos, G);
  k_i1<<<dim3(64, 11), dim3(256), 0, stream>>>(G, Bi);
  k_i2<<<dim3(64, 4, 5), dim3(256), 0, stream>>>(Bi, mol);
  k_proj<<<dim3(250), dim3(512), 0, stream>>>(mol, W, part);
  k_red<<<dim3(64, 4), dim3(256), 0, stream>>>(part, bias, out);
}

// Round 3
// 166.831 us; speedup vs baseline: 1.1452x; 1.1111x over previous
//
#include <hip/hip_runtime.h>

#define PI2 6.28318530717958647692f

// D = 10000 = 100 x 100; F = 5001; signals: 128 pos + 10 atom + 1 closure = 139
#define NSIG 139
#define FS   5120      // spectrum row stride (float2)

// ---------------- fused forward (f1+f2), Hermitian-paired, radix-4 folded ----------------
// Stage twiddles at stride 25 are exactly i^{k*h}: fold x (and the phase-2 rows) into
// 4 sign-combination tables (adds only), cutting both DFT inner loops 100 -> 25 iters.
__global__ __launch_bounds__(256) void k_fwd(
                     const float* __restrict__ atom, const float* __restrict__ pos,
                     const float* __restrict__ clo, float2* __restrict__ spec) {
  __shared__ float lds[10000];   // 40 KB union: phase1 tables / phase3 xs+tables
  unsigned sig = blockIdx.x, q = blockIdx.y;
  unsigned k1base = q * 10u;
  unsigned nk1 = (k1base + 10u <= 51u) ? 10u : (51u - k1base);   // q=5 -> 1 (k1=50)
  const float* xb = (sig < 128u) ? (pos + sig * 10000u)
                   : ((sig < 138u) ? (atom + (sig - 128u) * 10000u) : clo);
  int tid = threadIdx.x;

  // ---- phase 1a: radix-4 fold of x. Per (n1l, n2quad): A=sum, B=alt, G=x0-x2, H=x1-x3.
  // x real -> C[m] for m=k1&3 is {A,0},{G,H},{B,0},{G,-H}. Tables: 4 x 625 float4 = 40 KB.
  {
    float* csA = lds;
    float* csB = lds + 2500;
    float* csG = lds + 5000;
    float* csH = lds + 7500;
    for (int t2 = tid; t2 < 625; t2 += 256) {
      const float* p = xb + (t2 / 25) * 100 + (t2 % 25) * 4;
      float4 x0 = *(const float4*)(p);
      float4 x1 = *(const float4*)(p + 2500);
      float4 x2 = *(const float4*)(p + 5000);
      float4 x3 = *(const float4*)(p + 7500);
      float4 A, B, G, H;
      A.x = (x0.x + x2.x) + (x1.x + x3.x);
      A.y = (x0.y + x2.y) + (x1.y + x3.y);
      A.z = (x0.z + x2.z) + (x1.z + x3.z);
      A.w = (x0.w + x2.w) + (x1.w + x3.w);
      B.x = (x0.x + x2.x) - (x1.x + x3.x);
      B.y = (x0.y + x2.y) - (x1.y + x3.y);
      B.z = (x0.z + x2.z) - (x1.z + x3.z);
      B.w = (x0.w + x2.w) - (x1.w + x3.w);
      G.x = x0.x - x2.x;  G.y = x0.y - x2.y;
      G.z = x0.z - x2.z;  G.w = x0.w - x2.w;
      H.x = x1.x - x3.x;  H.y = x1.y - x3.y;
      H.z = x1.z - x3.z;  H.w = x1.w - x3.w;
      *(float4*)(csA + t2 * 4) = A;
      *(float4*)(csB + t2 * 4) = B;
      *(float4*)(csG + t2 * 4) = G;
      *(float4*)(csH + t2 * 4) = H;
    }
  }
  __syncthreads();

  // ---- phase 1b: 25-iter folded DFT + phase-2 twiddles (registers only) ----
  unsigned ntile1 = nk1 * 25u;
  unsigned k1l = tid / 25u, n2q = (unsigned)tid % 25u, n2 = n2q * 4u;
  bool have = (unsigned)tid < ntile1;
  unsigned k1 = k1base + k1l;
  float resA[8], resB[8];
  if (have) {
    float cth, sth;
    __sincosf(PI2 * (float)k1 * 0.01f, &sth, &cth);
    unsigned m = k1 & 3u;
    const float4* creP = (const float4*)((m == 0u) ? lds
                          : (m == 2u) ? (lds + 2500) : (lds + 5000)) + n2q;
    const float4* cimP = (const float4*)(lds + 7500) + n2q;
    float im_mul = (m == 1u) ? 1.0f : (m == 3u) ? -1.0f : 0.0f;
    float c = 1.0f, s = 0.0f;
    float ar[4] = {}, as[4] = {};
#pragma unroll 5
    for (int n1l = 0; n1l < 25; ++n1l) {
      float4 Cre = creP[n1l * 25];
      float4 Cim = cimP[n1l * 25];
      float se = im_mul * s, ce = im_mul * c;
      ar[0] += Cre.x * c - Cim.x * se;  as[0] += Cim.x * ce + Cre.x * s;
      ar[1] += Cre.y * c - Cim.y * se;  as[1] += Cim.y * ce + Cre.y * s;
      ar[2] += Cre.z * c - Cim.z * se;  as[2] += Cim.z * ce + Cre.z * s;
      ar[3] += Cre.w * c - Cim.w * se;  as[3] += Cim.w * ce + Cre.w * s;
      float cn = c * cth - s * sth;
      float sn = s * cth + c * sth;
      c = cn; s = sn;
    }
    unsigned rb = (100u - k1) % 100u;
#pragma unroll
    for (int j = 0; j < 4; ++j) {
      float swA, cwA, swB, cwB;
      __sincosf(PI2 * (float)((n2 + j) * k1) * 1e-4f, &swA, &cwA);
      __sincosf(PI2 * (float)((n2 + j) * rb) * 1e-4f, &swB, &cwB);
      resA[2 * j + 0] = ar[j] * cwA - as[j] * swA;
      resA[2 * j + 1] = -(as[j] * cwA + ar[j] * swA);
      resB[2 * j + 0] = ar[j] * cwB + as[j] * swB;
      resB[2 * j + 1] = as[j] * cwB - ar[j] * swB;
    }
  }
  __syncthreads();   // phase-1 tables dead; lds reused as xs below
  float* xs = lds;   // nrow x 200 floats (<= 4000)
  if (have) {
    float* pA = xs + k1l * 200u + n2 * 2u;
    float* pB = xs + (nk1 + k1l) * 200u + n2 * 2u;
    *(float4*)(pA + 0) = make_float4(resA[0], resA[1], resA[2], resA[3]);
    *(float4*)(pA + 4) = make_float4(resA[4], resA[5], resA[6], resA[7]);
    *(float4*)(pB + 0) = make_float4(resB[0], resB[1], resB[2], resB[3]);
    *(float4*)(pB + 4) = make_float4(resB[4], resB[5], resB[6], resB[7]);
  }
  __syncthreads();

  // ---- phase 3a: radix-4 fold of the complex rows (e^{-i} direction).
  // Per (row, n2l): cse = {C0.re, C0.im, C2.re, C2.im}; cso = {P, Q, R, T}
  // with P=re0-re2, Q=im1-im3, R=im0-im2, T=re1-re3.
  unsigned nrow = 2u * nk1;
  float* cse = lds + 4000;
  float* cso = lds + 6000;
  for (int t3 = tid; t3 < (int)(nrow * 25u); t3 += 256) {
    const float* br = xs + (t3 / 25) * 200;
    int n2l = t3 % 25;
    float2 b0 = *(const float2*)(br + 2 * n2l);
    float2 b1 = *(const float2*)(br + 2 * (25 + n2l));
    float2 b2 = *(const float2*)(br + 2 * (50 + n2l));
    float2 b3 = *(const float2*)(br + 2 * (75 + n2l));
    float4 e, o;
    e.x = (b0.x + b2.x) + (b1.x + b3.x);
    e.y = (b0.y + b2.y) + (b1.y + b3.y);
    e.z = (b0.x + b2.x) - (b1.x + b3.x);
    e.w = (b0.y + b2.y) - (b1.y + b3.y);
    o.x = b0.x - b2.x;   // P
    o.y = b1.y - b3.y;   // Q
    o.z = b0.y - b2.y;   // R
    o.w = b1.x - b3.x;   // T
    *(float4*)(cse + t3 * 4) = e;
    *(float4*)(cso + t3 * 4) = o;
  }
  __syncthreads();

  // ---- phase 3b: 25-iter folded second-stage DFT.
  // Even output k2: C = C0 or C2 (by k2&2). Odd output k2+1: C1=(P+Q,R-T), C3=(P-Q,R+T).
  unsigned ntile3 = nrow * 26u;
  for (unsigned t = tid; t < ntile3; t += 256u) {
    unsigned lr = t / 26u, k2 = (t % 26u) * 2u;
    unsigned gk1 = (lr < nk1) ? (k1base + lr) : ((100u - (k1base + (lr - nk1))) % 100u);
    float cthA, sthA, cthB, sthB;
    __sincosf(PI2 * (float)k2 * 0.01f, &sthA, &cthA);
    __sincosf(PI2 * (float)(k2 + 1) * 0.01f, &sthB, &cthB);
    bool hi = (k2 & 2u) != 0u;
    float sq = hi ? -1.0f : 1.0f;
    const float4* pe = (const float4*)(cse + lr * 100);
    const float4* po = (const float4*)(cso + lr * 100);
    float cA = 1.0f, sA = 0.0f, cB = 1.0f, sB = 0.0f;
    float reA = 0.f, imA = 0.f, reB = 0.f, imB = 0.f;
#pragma unroll 5
    for (int n2l = 0; n2l < 25; ++n2l) {
      float4 e = pe[n2l];
      float4 o = po[n2l];
      float car = hi ? e.z : e.x;
      float cai = hi ? e.w : e.y;
      float cbr = o.x + sq * o.y;
      float cbi = o.z - sq * o.w;
      reA += car * cA + cai * sA;  imA += cai * cA - car * sA;
      reB += cbr * cB + cbi * sB;  imB += cbi * cB - cbr * sB;
      float cA1 = cA * cthA - sA * sthA, sA1 = sA * cthA + cA * sthA;
      float cB1 = cB * cthB - sB * sthB, sB1 = sB * cthB + cB * sthB;
      cA = cA1; sA = sA1; cB = cB1; sB = sB1;
    }
    unsigned kA = gk1 + 100u * k2;
    unsigned kB = gk1 + 100u * (k2 + 1);
    if (kA <= 5000u) spec[sig * FS + kA] = make_float2(reA, imA);
    if (kB <= 5000u) spec[sig * FS + kB] = make_float2(reB, imB);
  }
}

// ---------------- mix: b-tile 4, k-chunk 128, 2-way s-split; grid (40,16) = 640 blocks ----------------
__global__ __launch_bounds__(256) void k_mix(const float2* __restrict__ spec,
                      const float* __restrict__ tmask, const float* __restrict__ rmask,
                      const int* __restrict__ aidx, const int* __restrict__ rpos,
                      float2* __restrict__ G) {
  __shared__ float2 FaS[10][128];
  __shared__ float2 FcS[128];
  __shared__ float tmS[4][128];
  __shared__ int   aiS[4][128];
  __shared__ float rmS[4][8];
  __shared__ int   rpS[4][8][2];
  __shared__ float2 red[2][4][128];
  int tid = threadIdx.x;
  int kl = tid & 127, half = tid >> 7;
  int k = blockIdx.x * 128 + kl;
  int kc = k > 5000 ? 5000 : k;
  int b0 = blockIdx.y * 4;
  for (int i = tid; i < 10 * 128; i += 256) {
    int a = i >> 7, kk = i & 127;
    int kg = blockIdx.x * 128 + kk; if (kg > 5000) kg = 5000;
    FaS[a][kk] = spec[(128 + a) * FS + kg];
  }
  if (tid < 128) FcS[tid] = spec[138 * FS + kc];
  for (int i = tid; i < 4 * 128; i += 256) {
    int bb = i >> 7, ss = i & 127;
    tmS[bb][ss] = tmask[(b0 + bb) * 128 + ss];
    aiS[bb][ss] = aidx[(b0 + bb) * 128 + ss];
  }
  if (tid < 32) {
    int bb = tid >> 3, rr = tid & 7;
    rmS[bb][rr] = rmask[(b0 + bb) * 8 + rr];
    rpS[bb][rr][0] = rpos[((b0 + bb) * 8 + rr) * 2 + 0];
    rpS[bb][rr][1] = rpos[((b0 + bb) * 8 + rr) * 2 + 1];
  }
  __syncthreads();
  float fr[4] = {}, fi[4] = {};
  int sbase = half * 64;
#pragma unroll 8
  for (int si = 0; si < 64; ++si) {
    int s = sbase + si;
    float2 fp = spec[s * FS + kc];
#pragma unroll
    for (int b = 0; b < 4; ++b) {
      int a = aiS[b][s];
      float tm = tmS[b][s];
      float2 fa = FaS[a][kl];
      fr[b] += tm * (fa.x * fp.x - fa.y * fp.y);
      fi[b] += tm * (fa.x * fp.y + fa.y * fp.x);
    }
  }
  float2 fc = FcS[kl];
#pragma unroll
  for (int rr = 0; rr < 4; ++rr) {
    int r = half * 4 + rr;
#pragma unroll
    for (int b = 0; b < 4; ++b) {
      int p0 = rpS[b][r][0], p1 = rpS[b][r][1];
      float rm = rmS[b][r];
      float2 f0 = spec[p0 * FS + kc];
      float2 f1 = spec[p1 * FS + kc];
      float tr = f0.x * f1.x - f0.y * f1.y;
      float ti = f0.x * f1.y + f0.y * f1.x;
      fr[b] += rm * (tr * fc.x - ti * fc.y);
      fi[b] += rm * (tr * fc.y + ti * fc.x);
    }
  }
#pragma unroll
  for (int b = 0; b < 4; ++b) red[half][b][kl] = make_float2(fr[b], fi[b]);
  __syncthreads();
  if (k <= 5000) {
#pragma unroll
    for (int j = 0; j < 2; ++j) {
      int b = half + 2 * j;
      float R = red[0][b][kl].x + red[1][b][kl].x;
      float I = red[0][b][kl].y + red[1][b][kl].y;
      if (k == 0 || k == 5000) I = 0.0f;   // exact Hermitian guard
      G[(size_t)(b0 + b) * 10000 + k] = make_float2(R, I);
      if (k >= 1 && k <= 4999)
        G[(size_t)(b0 + b) * 10000 + (10000 - k)] = make_float2(R, -I);
    }
  }
}

// ---------------- inverse stage 1: radix-4 folded (e^{+i} direction), LDS tables ----------------
// C[m] for m=m1&3: C0=sum, C2=alt, C1=(P-Q, R+T), C3=(P+Q, R-T); branchless qmul select.
__global__ __launch_bounds__(256) void k_i1(const float2* __restrict__ G,
                                            float2* __restrict__ Bi) {
  __shared__ float lds[10400];   // 4 tables x [25][26] float4 = 41.6 KB
  unsigned sig = blockIdx.x;
  const float* gp = (const float*)(G + sig * 10000u);
  int tid = threadIdx.x;
  float* c0v = lds;          // {C0.re(n2), C0.im(n2), C0.re(n2+1), C0.im(n2+1)}
  float* c2v = lds + 2600;
  float* cpr = lds + 5200;   // {P, R, P', R'}
  float* cqt = lds + 7800;   // {Q, T, Q', T'}
  for (int t2 = tid; t2 < 650; t2 += 256) {
    const float* p = gp + (t2 / 26) * 200 + (t2 % 26) * 4;
    float4 g0 = *(const float4*)(p);
    float4 g1 = *(const float4*)(p + 5000);
    float4 g2 = *(const float4*)(p + 10000);
    float4 g3 = *(const float4*)(p + 15000);
    float4 a, b, pr, qt;
    a.x = (g0.x + g2.x) + (g1.x + g3.x);
    a.y = (g0.y + g2.y) + (g1.y + g3.y);
    a.z = (g0.z + g2.z) + (g1.z + g3.z);
    a.w = (g0.w + g2.w) + (g1.w + g3.w);
    b.x = (g0.x + g2.x) - (g1.x + g3.x);
    b.y = (g0.y + g2.y) - (g1.y + g3.y);
    b.z = (g0.z + g2.z) - (g1.z + g3.z);
    b.w = (g0.w + g2.w) - (g1.w + g3.w);
    pr.x = g0.x - g2.x;  pr.y = g0.y - g2.y;
    pr.z = g0.z - g2.z;  pr.w = g0.w - g2.w;
    qt.x = g1.y - g3.y;  qt.y = g1.x - g3.x;
    qt.z = g1.w - g3.w;  qt.w = g1.z - g3.z;
    *(float4*)(c0v + t2 * 4) = a;
    *(float4*)(c2v + t2 * 4) = b;
    *(float4*)(cpr + t2 * 4) = pr;
    *(float4*)(cqt + t2 * 4) = qt;
  }
  __syncthreads();
  unsigned t = blockIdx.y * 256u + tid;
  if (t >= 2600u) return;
  unsigned m1 = t / 26u, n2p = t % 26u, n2 = n2p * 2u;
  float cth, sth;
  __sincosf(PI2 * (float)m1 * 0.01f, &sth, &cth);
  unsigned m = m1 & 3u;
  const float4* pe = (const float4*)((m == 0u) ? c0v : (m == 2u) ? c2v : cpr) + n2p;
  const float4* pq = (const float4*)cqt + n2p;
  float qmul = (m == 1u) ? -1.0f : (m == 3u) ? 1.0f : 0.0f;
  float c = 1.0f, s = 0.0f;
  float reA = 0.f, imA = 0.f, reB = 0.f, imB = 0.f;
#pragma unroll 5
  for (int n1l = 0; n1l < 25; ++n1l) {
    float4 ev = pe[n1l * 26];
    float4 qv = pq[n1l * 26];
    float gx = ev.x + qmul * qv.x;
    float gy = ev.y - qmul * qv.y;
    float gz = ev.z + qmul * qv.z;
    float gw = ev.w - qmul * qv.w;
    reA += gx * c - gy * s;  imA += gy * c + gx * s;
    reB += gz * c - gw * s;  imB += gw * c + gz * s;
    float cn = c * cth - s * sth;
    float sn = s * cth + c * sth;
    c = cn; s = sn;
  }
  float w0 = (n2 == 0u || n2 == 50u) ? 0.5f : 1.0f;
  float w1 = (n2 == 50u) ? 0.0f : 1.0f;   // col 51 unused
  float sw0, cw0, sw1, cw1;
  __sincosf(PI2 * (float)(n2 * m1) * 1e-4f, &sw0, &cw0);
  __sincosf(PI2 * (float)((n2 + 1u) * m1) * 1e-4f, &sw1, &cw1);
  float4 outv;
  outv.x = (reA * cw0 - imA * sw0) * w0;
  outv.y = (imA * cw0 + reA * sw0) * w0;
  outv.z = (reB * cw1 - imB * sw1) * w1;
  outv.w = (imB * cw1 + reB * sw1) * w1;
  *(float4*)((float*)Bi + (sig * 5200u + m1 * 52u + n2) * 2) = outv;
}

// ---------------- inverse stage 2: direct-global Bi reads (wave-broadcast, L1-hit) ----------------
__global__ __launch_bounds__(256) void k_i2(const float2* __restrict__ Bi,
                                            float* __restrict__ mol) {
  unsigned sig = blockIdx.x, q = blockIdx.y;
  int tid = threadIdx.x;
  unsigned t = blockIdx.z * 256u + tid;
  if (t >= 1250u) return;
  unsigned m1l = t / 50u;              // 0..24
  unsigned m2 = (t % 50u) * 2u;        // fastest
  const float* b0 = (const float*)Bi + sig * 10400u + q * 2600u + m1l * 104u;
  float cthA, sthA, cthB, sthB;
  __sincosf(PI2 * (float)m2 * 0.01f, &sthA, &cthA);
  __sincosf(PI2 * (float)(m2 + 1u) * 0.01f, &sthB, &cthB);
  float cA = 1.0f, sA = 0.0f, cB = 1.0f, sB = 0.0f;
  float r0 = 0.f, r1 = 0.f;
#pragma unroll 4
  for (int jj = 0; jj < 26; ++jj) {
    int n2i = 2 * jj;
    const float4 v0 = *(const float4*)(b0 + 2 * n2i);
    r0 += v0.x * cA - v0.y * sA;
    r1 += v0.x * cB - v0.y * sB;
    float cA1 = cA * cthA - sA * sthA, sA1 = sA * cthA + cA * sthA;
    float cB1 = cB * cthB - sB * sthB, sB1 = sB * cthB + cB * sthB;
    r0 += v0.z * cA1 - v0.w * sA1;
    r1 += v0.z * cB1 - v0.w * sB1;
    cA = cA1 * cthA - sA1 * sthA; sA = sA1 * cthA + cA1 * sthA;
    cB = cB1 * cthB - sB1 * sthB; sB = sB1 * cthB + cB1 * sthB;
  }
  unsigned m1 = q * 25u + m1l;
  mol[sig * 10000u + m1 + 100u * m2] = r0 * 2e-4f;
  mol[sig * 10000u + m1 + 100u * (m2 + 1u)] = r1 * 2e-4f;
}

// ---------------- projection: LDS-transposed W + mol (coalesced global, conflict-light LDS) ----------------
__global__ __launch_bounds__(512) void k_proj(const float* __restrict__ mol,
                                              const float* __restrict__ W,
                                              float* __restrict__ part) {
  __shared__ float molS[40 * 66];      // [dl][b] padded
  __shared__ float WS[40][258];        // [dl][p] padded
  int tid = threadIdx.x;
  int d0 = blockIdx.x * 40;
  for (int i = tid; i < 40 * 64; i += 512) {
    int b = i / 40, dl = i % 40;
    molS[dl * 66 + b] = mol[(size_t)b * 10000 + d0 + dl];
  }
  for (int i = tid; i < 40 * 256; i += 512) {
    int p = i / 40, dl = i % 40;
    WS[dl][p] = W[(size_t)p * 10000 + d0 + dl];
  }
  __syncthreads();
  int p0 = (tid & 127) * 2;
  int bh = (tid >> 7) * 16;
  float acc[2][16] = {};
#pragma unroll 4
  for (int dl = 0; dl < 40; ++dl) {
    const float2 wv = *(const float2*)(&WS[dl][p0]);
    const float2* m2p = (const float2*)(molS + dl * 66 + bh);
#pragma unroll
    for (int qq = 0; qq < 8; ++qq) {
      float2 mv = m2p[qq];
      acc[0][2 * qq + 0] += wv.x * mv.x;  acc[1][2 * qq + 0] += wv.y * mv.x;
      acc[0][2 * qq + 1] += wv.x * mv.y;  acc[1][2 * qq + 1] += wv.y * mv.y;
    }
  }
#pragma unroll
  for (int b = 0; b < 16; ++b)
    *(float2*)(part + (size_t)blockIdx.x * 16384 + (bh + b) * 256 + p0) =
        make_float2(acc[0][b], acc[1][b]);
}

// ---------------- reduce partials + bias: grid (64 b, 4 p-quarters), 256 threads, 4 chunk-groups ----------------
__global__ __launch_bounds__(256) void k_red(const float* __restrict__ part,
                                             const float* __restrict__ bias,
                                             float* __restrict__ out) {
  __shared__ float red[4][64];
  int tid = threadIdx.x;
  int pl = tid & 63, cg = tid >> 6;
  int b = blockIdx.x;
  int p = blockIdx.y * 64 + pl;
  float acc = 0.0f;
#pragma unroll 8
  for (int ch = cg; ch < 250; ch += 4)
    acc += part[(size_t)ch * 16384 + b * 256 + p];
  red[cg][pl] = acc;
  __syncthreads();
  if (tid < 64)
    out[b * 256 + p] = red[0][pl] + red[1][pl] + red[2][pl] + red[3][pl] + bias[p];
}

extern "C" void kernel_launch(void* const* d_in, const int* in_sizes, int n_in,
                              void* d_out, int out_size, void* d_ws, size_t ws_size,
                              hipStream_t stream) {
  const float* atom  = (const float*)d_in[0];   // [10,10000]
  const float* pos   = (const float*)d_in[1];   // [128,10000]
  const float* clo   = (const float*)d_in[2];   // [10000]
  const float* W     = (const float*)d_in[3];   // [256,10000]
  const float* bias  = (const float*)d_in[4];   // [256]
  const float* tmask = (const float*)d_in[5];   // [64,128]
  const float* rmask = (const float*)d_in[6];   // [64,8]
  const int*   aidx  = (const int*)d_in[7];     // [64,128]
  const int*   rpos  = (const int*)d_in[8];     // [64,8,2]
  float* out = (float*)d_out;                   // [64,256]

  char* ws = (char*)d_ws;
  size_t off = 0;
  auto alloc = [&](size_t n) { off = (off + 255) & ~(size_t)255; size_t o = off; off += n; return o; };
  char* regA   = ws + alloc(16777216);          // Bi (2.66MB) / partials (16.4MB)
  float2* Bi   = (float2*)regA;                 // i1/i2 use Bi before proj writes part
  float*  part = (float*)regA;
  float2* spec = (float2*)(ws + alloc((size_t)NSIG * FS * 8));
  float2* G    = (float2*)(ws + alloc((size_t)64 * 10000 * 8));
  float*  mol  = (float*)(ws + alloc((size_t)64 * 10000 * 4));

  k_fwd<<<dim3(NSIG, 6), dim3(256), 0, stream>>>(atom, pos, clo, spec);
  k_mix<<<dim3(40, 16), dim3(256), 0, stream>>>(spec, tmask, rmask, aidx, rpos, G);
  k_i1<<<dim3(64, 11), dim3(256), 0, stream>>>(G, Bi);
  k_i2<<<dim3(64, 4, 5), dim3(256), 0, stream>>>(Bi, mol);
  k_proj<<<dim3(250), dim3(512), 0, stream>>>(mol, W, part);
  k_red<<<dim3(64, 4), dim3(256), 0, stream>>>(part, bias, out);
}

// Round 4
// 161.405 us; speedup vs baseline: 1.1837x; 1.0336x over previous
//
#include <hip/hip_runtime.h>

#define PI2 6.28318530717958647692f

// D = 10000 = 100 x 100; F = 5001; signals: 128 pos + 10 atom + 1 closure = 139
#define NSIG 139
#define FS   5120      // spectrum row stride (float2)

// ---------------- fused forward (f1+f2), Hermitian-paired, radix-4 folded ----------------
__global__ __launch_bounds__(256) void k_fwd(
                     const float* __restrict__ atom, const float* __restrict__ pos,
                     const float* __restrict__ clo, float2* __restrict__ spec) {
  __shared__ float lds[10000];   // 40 KB union: phase1 tables / phase3 xs+tables
  unsigned sig = blockIdx.x, q = blockIdx.y;
  unsigned k1base = q * 10u;
  unsigned nk1 = (k1base + 10u <= 51u) ? 10u : (51u - k1base);   // q=5 -> 1 (k1=50)
  const float* xb = (sig < 128u) ? (pos + sig * 10000u)
                   : ((sig < 138u) ? (atom + (sig - 128u) * 10000u) : clo);
  int tid = threadIdx.x;

  // ---- phase 1a: radix-4 fold of x ----
  {
    float* csA = lds;
    float* csB = lds + 2500;
    float* csG = lds + 5000;
    float* csH = lds + 7500;
    for (int t2 = tid; t2 < 625; t2 += 256) {
      const float* p = xb + (t2 / 25) * 100 + (t2 % 25) * 4;
      float4 x0 = *(const float4*)(p);
      float4 x1 = *(const float4*)(p + 2500);
      float4 x2 = *(const float4*)(p + 5000);
      float4 x3 = *(const float4*)(p + 7500);
      float4 A, B, G, H;
      A.x = (x0.x + x2.x) + (x1.x + x3.x);
      A.y = (x0.y + x2.y) + (x1.y + x3.y);
      A.z = (x0.z + x2.z) + (x1.z + x3.z);
      A.w = (x0.w + x2.w) + (x1.w + x3.w);
      B.x = (x0.x + x2.x) - (x1.x + x3.x);
      B.y = (x0.y + x2.y) - (x1.y + x3.y);
      B.z = (x0.z + x2.z) - (x1.z + x3.z);
      B.w = (x0.w + x2.w) - (x1.w + x3.w);
      G.x = x0.x - x2.x;  G.y = x0.y - x2.y;
      G.z = x0.z - x2.z;  G.w = x0.w - x2.w;
      H.x = x1.x - x3.x;  H.y = x1.y - x3.y;
      H.z = x1.z - x3.z;  H.w = x1.w - x3.w;
      *(float4*)(csA + t2 * 4) = A;
      *(float4*)(csB + t2 * 4) = B;
      *(float4*)(csG + t2 * 4) = G;
      *(float4*)(csH + t2 * 4) = H;
    }
  }
  __syncthreads();

  // ---- phase 1b: 25-iter folded DFT + phase-2 twiddles ----
  unsigned ntile1 = nk1 * 25u;
  unsigned k1l = tid / 25u, n2q = (unsigned)tid % 25u, n2 = n2q * 4u;
  bool have = (unsigned)tid < ntile1;
  unsigned k1 = k1base + k1l;
  float resA[8], resB[8];
  if (have) {
    float cth, sth;
    __sincosf(PI2 * (float)k1 * 0.01f, &sth, &cth);
    unsigned m = k1 & 3u;
    const float4* creP = (const float4*)((m == 0u) ? lds
                          : (m == 2u) ? (lds + 2500) : (lds + 5000)) + n2q;
    const float4* cimP = (const float4*)(lds + 7500) + n2q;
    float im_mul = (m == 1u) ? 1.0f : (m == 3u) ? -1.0f : 0.0f;
    float c = 1.0f, s = 0.0f;
    float ar[4] = {}, as[4] = {};
#pragma unroll 5
    for (int n1l = 0; n1l < 25; ++n1l) {
      float4 Cre = creP[n1l * 25];
      float4 Cim = cimP[n1l * 25];
      float se = im_mul * s, ce = im_mul * c;
      ar[0] += Cre.x * c - Cim.x * se;  as[0] += Cim.x * ce + Cre.x * s;
      ar[1] += Cre.y * c - Cim.y * se;  as[1] += Cim.y * ce + Cre.y * s;
      ar[2] += Cre.z * c - Cim.z * se;  as[2] += Cim.z * ce + Cre.z * s;
      ar[3] += Cre.w * c - Cim.w * se;  as[3] += Cim.w * ce + Cre.w * s;
      float cn = c * cth - s * sth;
      float sn = s * cth + c * sth;
      c = cn; s = sn;
    }
    unsigned rb = (100u - k1) % 100u;
#pragma unroll
    for (int j = 0; j < 4; ++j) {
      float swA, cwA, swB, cwB;
      __sincosf(PI2 * (float)((n2 + j) * k1) * 1e-4f, &swA, &cwA);
      __sincosf(PI2 * (float)((n2 + j) * rb) * 1e-4f, &swB, &cwB);
      resA[2 * j + 0] = ar[j] * cwA - as[j] * swA;
      resA[2 * j + 1] = -(as[j] * cwA + ar[j] * swA);
      resB[2 * j + 0] = ar[j] * cwB + as[j] * swB;
      resB[2 * j + 1] = as[j] * cwB - ar[j] * swB;
    }
  }
  __syncthreads();   // phase-1 tables dead; lds reused as xs below
  float* xs = lds;   // nrow x 200 floats (<= 4000)
  if (have) {
    float* pA = xs + k1l * 200u + n2 * 2u;
    float* pB = xs + (nk1 + k1l) * 200u + n2 * 2u;
    *(float4*)(pA + 0) = make_float4(resA[0], resA[1], resA[2], resA[3]);
    *(float4*)(pA + 4) = make_float4(resA[4], resA[5], resA[6], resA[7]);
    *(float4*)(pB + 0) = make_float4(resB[0], resB[1], resB[2], resB[3]);
    *(float4*)(pB + 4) = make_float4(resB[4], resB[5], resB[6], resB[7]);
  }
  __syncthreads();

  // ---- phase 3a: radix-4 fold of the complex rows (e^{-i} direction) ----
  unsigned nrow = 2u * nk1;
  float* cse = lds + 4000;
  float* cso = lds + 6000;
  for (int t3 = tid; t3 < (int)(nrow * 25u); t3 += 256) {
    const float* br = xs + (t3 / 25) * 200;
    int n2l = t3 % 25;
    float2 b0 = *(const float2*)(br + 2 * n2l);
    float2 b1 = *(const float2*)(br + 2 * (25 + n2l));
    float2 b2 = *(const float2*)(br + 2 * (50 + n2l));
    float2 b3 = *(const float2*)(br + 2 * (75 + n2l));
    float4 e, o;
    e.x = (b0.x + b2.x) + (b1.x + b3.x);
    e.y = (b0.y + b2.y) + (b1.y + b3.y);
    e.z = (b0.x + b2.x) - (b1.x + b3.x);
    e.w = (b0.y + b2.y) - (b1.y + b3.y);
    o.x = b0.x - b2.x;   // P
    o.y = b1.y - b3.y;   // Q
    o.z = b0.y - b2.y;   // R
    o.w = b1.x - b3.x;   // T
    *(float4*)(cse + t3 * 4) = e;
    *(float4*)(cso + t3 * 4) = o;
  }
  __syncthreads();

  // ---- phase 3b: 25-iter folded second-stage DFT ----
  unsigned ntile3 = nrow * 26u;
  for (unsigned t = tid; t < ntile3; t += 256u) {
    unsigned lr = t / 26u, k2 = (t % 26u) * 2u;
    unsigned gk1 = (lr < nk1) ? (k1base + lr) : ((100u - (k1base + (lr - nk1))) % 100u);
    float cthA, sthA, cthB, sthB;
    __sincosf(PI2 * (float)k2 * 0.01f, &sthA, &cthA);
    __sincosf(PI2 * (float)(k2 + 1) * 0.01f, &sthB, &cthB);
    bool hi = (k2 & 2u) != 0u;
    float sq = hi ? -1.0f : 1.0f;
    const float4* pe = (const float4*)(cse + lr * 100);
    const float4* po = (const float4*)(cso + lr * 100);
    float cA = 1.0f, sA = 0.0f, cB = 1.0f, sB = 0.0f;
    float reA = 0.f, imA = 0.f, reB = 0.f, imB = 0.f;
#pragma unroll 5
    for (int n2l = 0; n2l < 25; ++n2l) {
      float4 e = pe[n2l];
      float4 o = po[n2l];
      float car = hi ? e.z : e.x;
      float cai = hi ? e.w : e.y;
      float cbr = o.x + sq * o.y;
      float cbi = o.z - sq * o.w;
      reA += car * cA + cai * sA;  imA += cai * cA - car * sA;
      reB += cbr * cB + cbi * sB;  imB += cbi * cB - cbr * sB;
      float cA1 = cA * cthA - sA * sthA, sA1 = sA * cthA + cA * sthA;
      float cB1 = cB * cthB - sB * sthB, sB1 = sB * cthB + cB * sthB;
      cA = cA1; sA = sA1; cB = cB1; sB = sB1;
    }
    unsigned kA = gk1 + 100u * k2;
    unsigned kB = gk1 + 100u * (k2 + 1);
    if (kA <= 5000u) spec[sig * FS + kA] = make_float2(reA, imA);
    if (kB <= 5000u) spec[sig * FS + kB] = make_float2(reB, imB);
  }
}

// ---------------- mix: b-tile 8, k-chunk 64, 4-way s-split; grid (80,8) = 640 blocks ----------------
// Spec s-loop traffic halved vs b-tile-4/k-128 (42 MB); same total VALU and block count.
__global__ __launch_bounds__(256) void k_mix(const float2* __restrict__ spec,
                      const float* __restrict__ tmask, const float* __restrict__ rmask,
                      const int* __restrict__ aidx, const int* __restrict__ rpos,
                      float2* __restrict__ G) {
  __shared__ float2 FaS[10][64];
  __shared__ float2 FcS[64];
  __shared__ float tmS[8][128];
  __shared__ int   aiS[8][128];
  __shared__ float rmS[8][8];
  __shared__ int   rpS[8][8][2];
  __shared__ float2 red[4][8][64];
  int tid = threadIdx.x;
  int kl = tid & 63, grp = tid >> 6;
  int k = blockIdx.x * 64 + kl;
  int kc = k > 5000 ? 5000 : k;
  int b0 = blockIdx.y * 8;
  for (int i = tid; i < 640; i += 256) {
    int a = i >> 6, kk = i & 63;
    int kg = blockIdx.x * 64 + kk; if (kg > 5000) kg = 5000;
    FaS[a][kk] = spec[(128 + a) * FS + kg];
  }
  if (tid < 64) FcS[tid] = spec[138 * FS + kc];
  for (int i = tid; i < 8 * 128; i += 256) {
    int bb = i >> 7, ss = i & 127;
    tmS[bb][ss] = tmask[(b0 + bb) * 128 + ss];
    aiS[bb][ss] = aidx[(b0 + bb) * 128 + ss];
  }
  if (tid < 64) {
    int bb = tid >> 3, rr = tid & 7;
    rmS[bb][rr] = rmask[(b0 + bb) * 8 + rr];
    rpS[bb][rr][0] = rpos[((b0 + bb) * 8 + rr) * 2 + 0];
    rpS[bb][rr][1] = rpos[((b0 + bb) * 8 + rr) * 2 + 1];
  }
  __syncthreads();
  float fr[8] = {}, fi[8] = {};
  int sbase = grp * 32;
#pragma unroll 4
  for (int si = 0; si < 32; ++si) {
    int s = sbase + si;
    float2 fp = spec[s * FS + kc];
#pragma unroll
    for (int b = 0; b < 8; ++b) {
      int a = aiS[b][s];
      float tm = tmS[b][s];
      float2 fa = FaS[a][kl];
      fr[b] += tm * (fa.x * fp.x - fa.y * fp.y);
      fi[b] += tm * (fa.x * fp.y + fa.y * fp.x);
    }
  }
  float2 fc = FcS[kl];
#pragma unroll
  for (int rr = 0; rr < 2; ++rr) {
    int r = grp * 2 + rr;
#pragma unroll
    for (int b = 0; b < 8; ++b) {
      int p0 = rpS[b][r][0], p1 = rpS[b][r][1];
      float rm = rmS[b][r];
      float2 f0 = spec[p0 * FS + kc];
      float2 f1 = spec[p1 * FS + kc];
      float tr = f0.x * f1.x - f0.y * f1.y;
      float ti = f0.x * f1.y + f0.y * f1.x;
      fr[b] += rm * (tr * fc.x - ti * fc.y);
      fi[b] += rm * (tr * fc.y + ti * fc.x);
    }
  }
#pragma unroll
  for (int b = 0; b < 8; ++b) red[grp][b][kl] = make_float2(fr[b], fi[b]);
  __syncthreads();
#pragma unroll
  for (int j = 0; j < 2; ++j) {
    int slot = j * 256 + tid;
    int b = slot >> 6, kk = slot & 63;
    int kg = blockIdx.x * 64 + kk;
    if (kg <= 5000) {
      float R = red[0][b][kk].x + red[1][b][kk].x + red[2][b][kk].x + red[3][b][kk].x;
      float I = red[0][b][kk].y + red[1][b][kk].y + red[2][b][kk].y + red[3][b][kk].y;
      if (kg == 0 || kg == 5000) I = 0.0f;   // exact Hermitian guard
      G[(size_t)(b0 + b) * 10000 + kg] = make_float2(R, I);
      if (kg >= 1 && kg <= 4999)
        G[(size_t)(b0 + b) * 10000 + (10000 - kg)] = make_float2(R, -I);
    }
  }
}

// ---------------- inverse stage 1: radix-4 folded + (m1, m1+50) pairing ----------------
// e^{i2pi(m1+50)n1/100} = (-1)^{n1} e^{i2pi m1 n1/100}; quarter-select m'=m^2, qmul2=-qmul.
__global__ __launch_bounds__(256) void k_i1(const float2* __restrict__ G,
                                            float2* __restrict__ Bi) {
  __shared__ float lds[10400];   // 4 tables x [25][26] float4 = 41.6 KB
  unsigned sig = blockIdx.x;
  const float* gp = (const float*)(G + sig * 10000u);
  int tid = threadIdx.x;
  float* c0v = lds;          // {C0.re(n2), C0.im(n2), C0.re(n2+1), C0.im(n2+1)}
  float* c2v = lds + 2600;
  float* cpr = lds + 5200;   // {P, R, P', R'}
  float* cqt = lds + 7800;   // {Q, T, Q', T'}
  for (int t2 = tid; t2 < 650; t2 += 256) {
    const float* p = gp + (t2 / 26) * 200 + (t2 % 26) * 4;
    float4 g0 = *(const float4*)(p);
    float4 g1 = *(const float4*)(p + 5000);
    float4 g2 = *(const float4*)(p + 10000);
    float4 g3 = *(const float4*)(p + 15000);
    float4 a, b, pr, qt;
    a.x = (g0.x + g2.x) + (g1.x + g3.x);
    a.y = (g0.y + g2.y) + (g1.y + g3.y);
    a.z = (g0.z + g2.z) + (g1.z + g3.z);
    a.w = (g0.w + g2.w) + (g1.w + g3.w);
    b.x = (g0.x + g2.x) - (g1.x + g3.x);
    b.y = (g0.y + g2.y) - (g1.y + g3.y);
    b.z = (g0.z + g2.z) - (g1.z + g3.z);
    b.w = (g0.w + g2.w) - (g1.w + g3.w);
    pr.x = g0.x - g2.x;  pr.y = g0.y - g2.y;
    pr.z = g0.z - g2.z;  pr.w = g0.w - g2.w;
    qt.x = g1.y - g3.y;  qt.y = g1.x - g3.x;
    qt.z = g1.w - g3.w;  qt.w = g1.z - g3.z;
    *(float4*)(c0v + t2 * 4) = a;
    *(float4*)(c2v + t2 * 4) = b;
    *(float4*)(cpr + t2 * 4) = pr;
    *(float4*)(cqt + t2 * 4) = qt;
  }
  __syncthreads();
  unsigned t = blockIdx.y * 256u + tid;
  if (t >= 1300u) return;
  unsigned m1 = t / 26u, n2p = t % 26u, n2 = n2p * 2u;   // m1 in [0,50)
  float cth, sth;
  __sincosf(PI2 * (float)m1 * 0.01f, &sth, &cth);
  unsigned m = m1 & 3u;
  const float4* pe  = (const float4*)((m == 0u) ? c0v : (m == 2u) ? c2v : cpr) + n2p;
  const float4* pe2 = (const float4*)((m == 0u) ? c2v : (m == 2u) ? c0v : cpr) + n2p;
  const float4* pq  = (const float4*)cqt + n2p;
  float qmul = (m == 1u) ? -1.0f : (m == 3u) ? 1.0f : 0.0f;
  float qmul2 = -qmul;
  float c = 1.0f, s = 0.0f, sg = 1.0f;
  float reA = 0.f, imA = 0.f, reB = 0.f, imB = 0.f;
  float reA2 = 0.f, imA2 = 0.f, reB2 = 0.f, imB2 = 0.f;
#pragma unroll 5
  for (int n1l = 0; n1l < 25; ++n1l) {
    float4 ev = pe[n1l * 26];
    float4 e2 = pe2[n1l * 26];
    float4 qv = pq[n1l * 26];
    float gx = ev.x + qmul * qv.x,  gy = ev.y - qmul * qv.y;
    float gz = ev.z + qmul * qv.z,  gw = ev.w - qmul * qv.w;
    float hx = e2.x + qmul2 * qv.x, hy = e2.y - qmul2 * qv.y;
    float hz = e2.z + qmul2 * qv.z, hw = e2.w - qmul2 * qv.w;
    reA += gx * c - gy * s;  imA += gy * c + gx * s;
    reB += gz * c - gw * s;  imB += gw * c + gz * s;
    float cs = sg * c, ss = sg * s;
    reA2 += hx * cs - hy * ss;  imA2 += hy * cs + hx * ss;
    reB2 += hz * cs - hw * ss;  imB2 += hw * cs + hz * ss;
    float cn = c * cth - s * sth;
    float sn = s * cth + c * sth;
    c = cn; s = sn; sg = -sg;
  }
  float w0 = (n2 == 0u || n2 == 50u) ? 0.5f : 1.0f;
  float w1 = (n2 == 50u) ? 0.0f : 1.0f;   // col 51 unused
  {
    float sw0, cw0, sw1, cw1;
    __sincosf(PI2 * (float)(n2 * m1) * 1e-4f, &sw0, &cw0);
    __sincosf(PI2 * (float)((n2 + 1u) * m1) * 1e-4f, &sw1, &cw1);
    float4 outv;
    outv.x = (reA * cw0 - imA * sw0) * w0;
    outv.y = (imA * cw0 + reA * sw0) * w0;
    outv.z = (reB * cw1 - imB * sw1) * w1;
    outv.w = (imB * cw1 + reB * sw1) * w1;
    *(float4*)((float*)Bi + (sig * 5200u + m1 * 52u + n2) * 2) = outv;
  }
  {
    unsigned m1b = m1 + 50u;
    float sw0, cw0, sw1, cw1;
    __sincosf(PI2 * (float)(n2 * m1b) * 1e-4f, &sw0, &cw0);
    __sincosf(PI2 * (float)((n2 + 1u) * m1b) * 1e-4f, &sw1, &cw1);
    float4 outv;
    outv.x = (reA2 * cw0 - imA2 * sw0) * w0;
    outv.y = (imA2 * cw0 + reA2 * sw0) * w0;
    outv.z = (reB2 * cw1 - imB2 * sw1) * w1;
    outv.w = (imB2 * cw1 + reB2 * sw1) * w1;
    *(float4*)((float*)Bi + (sig * 5200u + m1b * 52u + n2) * 2) = outv;
  }
}

// ---------------- inverse stage 2: (m2, m2+50) pairing via even/odd-n2 partial sums ----------------
__global__ __launch_bounds__(256) void k_i2(const float2* __restrict__ Bi,
                                            float* __restrict__ mol) {
  unsigned sig = blockIdx.x, q = blockIdx.y;
  int tid = threadIdx.x;
  unsigned t = blockIdx.z * 256u + tid;
  if (t >= 625u) return;
  unsigned m1l = t / 25u;              // 0..24
  unsigned m2 = (t % 25u) * 2u;        // 0..48 even
  const float* bp = (const float*)Bi + sig * 10400u + q * 2600u + m1l * 104u;
  float cthA, sthA, cthB, sthB;
  __sincosf(PI2 * (float)m2 * 0.01f, &sthA, &cthA);
  __sincosf(PI2 * (float)(m2 + 1u) * 0.01f, &sthB, &cthB);
  float cA = 1.0f, sA = 0.0f, cB = 1.0f, sB = 0.0f;
  float r0e = 0.f, r0o = 0.f, r1e = 0.f, r1o = 0.f;
#pragma unroll 4
  for (int jj = 0; jj < 26; ++jj) {
    const float4 v0 = *(const float4*)(bp + 4 * jj);
    r0e += v0.x * cA - v0.y * sA;      // n2 = 2jj (even)
    r1e += v0.x * cB - v0.y * sB;
    float cA1 = cA * cthA - sA * sthA, sA1 = sA * cthA + cA * sthA;
    float cB1 = cB * cthB - sB * sthB, sB1 = sB * cthB + cB * sthB;
    r0o += v0.z * cA1 - v0.w * sA1;    // n2 = 2jj+1 (odd)
    r1o += v0.z * cB1 - v0.w * sB1;
    cA = cA1 * cthA - sA1 * sthA; sA = sA1 * cthA + cA1 * sthA;
    cB = cB1 * cthB - sB1 * sthB; sB = sB1 * cthB + cB1 * sthB;
  }
  unsigned m1 = q * 25u + m1l;
  float* mp = mol + sig * 10000u + m1;
  mp[100u * m2]          = (r0e + r0o) * 2e-4f;
  mp[100u * (m2 + 1u)]   = (r1e + r1o) * 2e-4f;
  mp[100u * (m2 + 50u)]  = (r0e - r0o) * 2e-4f;
  mp[100u * (m2 + 51u)]  = (r1e - r1o) * 2e-4f;
}

// ---------------- projection: LDS-transposed W + mol ----------------
__global__ __launch_bounds__(512) void k_proj(const float* __restrict__ mol,
                                              const float* __restrict__ W,
                                              float* __restrict__ part) {
  __shared__ float molS[40 * 66];      // [dl][b] padded
  __shared__ float WS[40][258];        // [dl][p] padded
  int tid = threadIdx.x;
  int d0 = blockIdx.x * 40;
  for (int i = tid; i < 40 * 64; i += 512) {
    int b = i / 40, dl = i % 40;
    molS[dl * 66 + b] = mol[(size_t)b * 10000 + d0 + dl];
  }
  for (int i = tid; i < 40 * 256; i += 512) {
    int p = i / 40, dl = i % 40;
    WS[dl][p] = W[(size_t)p * 10000 + d0 + dl];
  }
  __syncthreads();
  int p0 = (tid & 127) * 2;
  int bh = (tid >> 7) * 16;
  float acc[2][16] = {};
#pragma unroll 4
  for (int dl = 0; dl < 40; ++dl) {
    const float2 wv = *(const float2*)(&WS[dl][p0]);
    const float2* m2p = (const float2*)(molS + dl * 66 + bh);
#pragma unroll
    for (int qq = 0; qq < 8; ++qq) {
      float2 mv = m2p[qq];
      acc[0][2 * qq + 0] += wv.x * mv.x;  acc[1][2 * qq + 0] += wv.y * mv.x;
      acc[0][2 * qq + 1] += wv.x * mv.y;  acc[1][2 * qq + 1] += wv.y * mv.y;
    }
  }
#pragma unroll
  for (int b = 0; b < 16; ++b)
    *(float2*)(part + (size_t)blockIdx.x * 16384 + (bh + b) * 256 + p0) =
        make_float2(acc[0][b], acc[1][b]);
}

// ---------------- reduce partials + bias ----------------
__global__ __launch_bounds__(256) void k_red(const float* __restrict__ part,
                                             const float* __restrict__ bias,
                                             float* __restrict__ out) {
  __shared__ float red[4][64];
  int tid = threadIdx.x;
  int pl = tid & 63, cg = tid >> 6;
  int b = blockIdx.x;
  int p = blockIdx.y * 64 + pl;
  float acc = 0.0f;
#pragma unroll 8
  for (int ch = cg; ch < 250; ch += 4)
    acc += part[(size_t)ch * 16384 + b * 256 + p];
  red[cg][pl] = acc;
  __syncthreads();
  if (tid < 64)
    out[b * 256 + p] = red[0][pl] + red[1][pl] + red[2][pl] + red[3][pl] + bias[p];
}

extern "C" void kernel_launch(void* const* d_in, const int* in_sizes, int n_in,
                              void* d_out, int out_size, void* d_ws, size_t ws_size,
                              hipStream_t stream) {
  const float* atom  = (const float*)d_in[0];   // [10,10000]
  const float* pos   = (const float*)d_in[1];   // [128,10000]
  const float* clo   = (const float*)d_in[2];   // [10000]
  const float* W     = (const float*)d_in[3];   // [256,10000]
  const float* bias  = (const float*)d_in[4];   // [256]
  const float* tmask = (const float*)d_in[5];   // [64,128]
  const float* rmask = (const float*)d_in[6];   // [64,8]
  const int*   aidx  = (const int*)d_in[7];     // [64,128]
  const int*   rpos  = (const int*)d_in[8];     // [64,8,2]
  float* out = (float*)d_out;                   // [64,256]

  char* ws = (char*)d_ws;
  size_t off = 0;
  auto alloc = [&](size_t n) { off = (off + 255) & ~(size_t)255; size_t o = off; off += n; return o; };
  char* regA   = ws + alloc(16777216);          // Bi (2.66MB) / partials (16.4MB)
  float2* Bi   = (float2*)regA;                 // i1/i2 use Bi before proj writes part
  float*  part = (float*)regA;
  float2* spec = (float2*)(ws + alloc((size_t)NSIG * FS * 8));
  float2* G    = (float2*)(ws + alloc((size_t)64 * 10000 * 8));
  float*  mol  = (float*)(ws + alloc((size_t)64 * 10000 * 4));

  k_fwd<<<dim3(NSIG, 6), dim3(256), 0, stream>>>(atom, pos, clo, spec);
  k_mix<<<dim3(80, 8), dim3(256), 0, stream>>>(spec, tmask, rmask, aidx, rpos, G);
  k_i1<<<dim3(64, 6), dim3(256), 0, stream>>>(G, Bi);
  k_i2<<<dim3(64, 4, 3), dim3(256), 0, stream>>>(Bi, mol);
  k_proj<<<dim3(250), dim3(512), 0, stream>>>(mol, W, part);
  k_red<<<dim3(64, 4), dim3(256), 0, stream>>>(part, bias, out);
}

// Round 5
// 158.630 us; speedup vs baseline: 1.2044x; 1.0175x over previous
//
#include <hip/hip_runtime.h>

#define PI2 6.28318530717958647692f

// D = 10000 = 100 x 100; F = 5001; signals: 128 pos + 10 atom + 1 closure = 139
#define NSIG 139
#define FS   5120      // spectrum row stride (float2)

// ---------------- fused forward (f1+f2), Hermitian-paired, radix-4 folded ----------------
__global__ __launch_bounds__(256) void k_fwd(
                     const float* __restrict__ atom, const float* __restrict__ pos,
                     const float* __restrict__ clo, float2* __restrict__ spec) {
  __shared__ float lds[10000];   // 40 KB union: phase1 tables / phase3 xs+tables
  unsigned sig = blockIdx.x, q = blockIdx.y;
  unsigned k1base = q * 10u;
  unsigned nk1 = (k1base + 10u <= 51u) ? 10u : (51u - k1base);   // q=5 -> 1 (k1=50)
  const float* xb = (sig < 128u) ? (pos + sig * 10000u)
                   : ((sig < 138u) ? (atom + (sig - 128u) * 10000u) : clo);
  int tid = threadIdx.x;

  // ---- phase 1a: radix-4 fold of x ----
  {
    float* csA = lds;
    float* csB = lds + 2500;
    float* csG = lds + 5000;
    float* csH = lds + 7500;
    for (int t2 = tid; t2 < 625; t2 += 256) {
      const float* p = xb + (t2 / 25) * 100 + (t2 % 25) * 4;
      float4 x0 = *(const float4*)(p);
      float4 x1 = *(const float4*)(p + 2500);
      float4 x2 = *(const float4*)(p + 5000);
      float4 x3 = *(const float4*)(p + 7500);
      float4 A, B, G, H;
      A.x = (x0.x + x2.x) + (x1.x + x3.x);
      A.y = (x0.y + x2.y) + (x1.y + x3.y);
      A.z = (x0.z + x2.z) + (x1.z + x3.z);
      A.w = (x0.w + x2.w) + (x1.w + x3.w);
      B.x = (x0.x + x2.x) - (x1.x + x3.x);
      B.y = (x0.y + x2.y) - (x1.y + x3.y);
      B.z = (x0.z + x2.z) - (x1.z + x3.z);
      B.w = (x0.w + x2.w) - (x1.w + x3.w);
      G.x = x0.x - x2.x;  G.y = x0.y - x2.y;
      G.z = x0.z - x2.z;  G.w = x0.w - x2.w;
      H.x = x1.x - x3.x;  H.y = x1.y - x3.y;
      H.z = x1.z - x3.z;  H.w = x1.w - x3.w;
      *(float4*)(csA + t2 * 4) = A;
      *(float4*)(csB + t2 * 4) = B;
      *(float4*)(csG + t2 * 4) = G;
      *(float4*)(csH + t2 * 4) = H;
    }
  }
  __syncthreads();

  // ---- phase 1b: 25-iter folded DFT + phase-2 twiddles ----
  unsigned ntile1 = nk1 * 25u;
  unsigned k1l = tid / 25u, n2q = (unsigned)tid % 25u, n2 = n2q * 4u;
  bool have = (unsigned)tid < ntile1;
  unsigned k1 = k1base + k1l;
  float resA[8], resB[8];
  if (have) {
    float cth, sth;
    __sincosf(PI2 * (float)k1 * 0.01f, &sth, &cth);
    unsigned m = k1 & 3u;
    const float4* creP = (const float4*)((m == 0u) ? lds
                          : (m == 2u) ? (lds + 2500) : (lds + 5000)) + n2q;
    const float4* cimP = (const float4*)(lds + 7500) + n2q;
    float im_mul = (m == 1u) ? 1.0f : (m == 3u) ? -1.0f : 0.0f;
    float c = 1.0f, s = 0.0f;
    float ar[4] = {}, as[4] = {};
#pragma unroll 5
    for (int n1l = 0; n1l < 25; ++n1l) {
      float4 Cre = creP[n1l * 25];
      float4 Cim = cimP[n1l * 25];
      float se = im_mul * s, ce = im_mul * c;
      ar[0] += Cre.x * c - Cim.x * se;  as[0] += Cim.x * ce + Cre.x * s;
      ar[1] += Cre.y * c - Cim.y * se;  as[1] += Cim.y * ce + Cre.y * s;
      ar[2] += Cre.z * c - Cim.z * se;  as[2] += Cim.z * ce + Cre.z * s;
      ar[3] += Cre.w * c - Cim.w * se;  as[3] += Cim.w * ce + Cre.w * s;
      float cn = c * cth - s * sth;
      float sn = s * cth + c * sth;
      c = cn; s = sn;
    }
    unsigned rb = (100u - k1) % 100u;
#pragma unroll
    for (int j = 0; j < 4; ++j) {
      float swA, cwA, swB, cwB;
      __sincosf(PI2 * (float)((n2 + j) * k1) * 1e-4f, &swA, &cwA);
      __sincosf(PI2 * (float)((n2 + j) * rb) * 1e-4f, &swB, &cwB);
      resA[2 * j + 0] = ar[j] * cwA - as[j] * swA;
      resA[2 * j + 1] = -(as[j] * cwA + ar[j] * swA);
      resB[2 * j + 0] = ar[j] * cwB + as[j] * swB;
      resB[2 * j + 1] = as[j] * cwB - ar[j] * swB;
    }
  }
  __syncthreads();   // phase-1 tables dead; lds reused as xs below
  float* xs = lds;   // nrow x 200 floats (<= 4000)
  if (have) {
    float* pA = xs + k1l * 200u + n2 * 2u;
    float* pB = xs + (nk1 + k1l) * 200u + n2 * 2u;
    *(float4*)(pA + 0) = make_float4(resA[0], resA[1], resA[2], resA[3]);
    *(float4*)(pA + 4) = make_float4(resA[4], resA[5], resA[6], resA[7]);
    *(float4*)(pB + 0) = make_float4(resB[0], resB[1], resB[2], resB[3]);
    *(float4*)(pB + 4) = make_float4(resB[4], resB[5], resB[6], resB[7]);
  }
  __syncthreads();

  // ---- phase 3a: radix-4 fold of the complex rows (e^{-i} direction) ----
  unsigned nrow = 2u * nk1;
  float* cse = lds + 4000;
  float* cso = lds + 6000;
  for (int t3 = tid; t3 < (int)(nrow * 25u); t3 += 256) {
    const float* br = xs + (t3 / 25) * 200;
    int n2l = t3 % 25;
    float2 b0 = *(const float2*)(br + 2 * n2l);
    float2 b1 = *(const float2*)(br + 2 * (25 + n2l));
    float2 b2 = *(const float2*)(br + 2 * (50 + n2l));
    float2 b3 = *(const float2*)(br + 2 * (75 + n2l));
    float4 e, o;
    e.x = (b0.x + b2.x) + (b1.x + b3.x);
    e.y = (b0.y + b2.y) + (b1.y + b3.y);
    e.z = (b0.x + b2.x) - (b1.x + b3.x);
    e.w = (b0.y + b2.y) - (b1.y + b3.y);
    o.x = b0.x - b2.x;   // P
    o.y = b1.y - b3.y;   // Q
    o.z = b0.y - b2.y;   // R
    o.w = b1.x - b3.x;   // T
    *(float4*)(cse + t3 * 4) = e;
    *(float4*)(cso + t3 * 4) = o;
  }
  __syncthreads();

  // ---- phase 3b: 25 uniform k2-pairs (k2 <= 48); stores unconditional (kA<=4899, kB<=4999) ----
  unsigned ntile3 = nrow * 25u;
  for (unsigned t = tid; t < ntile3; t += 256u) {
    unsigned lr = t / 25u, k2 = (t % 25u) * 2u;
    unsigned gk1 = (lr < nk1) ? (k1base + lr) : ((100u - (k1base + (lr - nk1))) % 100u);
    float cthA, sthA, cthB, sthB;
    __sincosf(PI2 * (float)k2 * 0.01f, &sthA, &cthA);
    __sincosf(PI2 * (float)(k2 + 1) * 0.01f, &sthB, &cthB);
    bool hi = (k2 & 2u) != 0u;
    float sq = hi ? -1.0f : 1.0f;
    const float4* pe = (const float4*)(cse + lr * 100);
    const float4* po = (const float4*)(cso + lr * 100);
    float cA = 1.0f, sA = 0.0f, cB = 1.0f, sB = 0.0f;
    float reA = 0.f, imA = 0.f, reB = 0.f, imB = 0.f;
#pragma unroll 5
    for (int n2l = 0; n2l < 25; ++n2l) {
      float4 e = pe[n2l];
      float4 o = po[n2l];
      float car = hi ? e.z : e.x;
      float cai = hi ? e.w : e.y;
      float cbr = o.x + sq * o.y;
      float cbi = o.z - sq * o.w;
      reA += car * cA + cai * sA;  imA += cai * cA - car * sA;
      reB += cbr * cB + cbi * sB;  imB += cbi * cB - cbr * sB;
      float cA1 = cA * cthA - sA * sthA, sA1 = sA * cthA + cA * sthA;
      float cB1 = cB * cthB - sB * sthB, sB1 = sB * cthB + cB * sthB;
      cA = cA1; sA = sA1; cB = cB1; sB = sB1;
    }
    unsigned kA = gk1 + 100u * k2;
    spec[sig * FS + kA] = make_float2(reA, imA);
    spec[sig * FS + kA + 100u] = make_float2(reB, imB);
  }
  // k2 = 50: only gk1 = 0 survives (kA = 5000); hi=true table, twiddle (-1)^n2l
  if (k1base == 0u && tid == 255) {
    const float4* pe = (const float4*)(cse);   // lr = 0 (gk1 = 0)
    float c = 1.0f, re = 0.f, im = 0.f;
#pragma unroll 5
    for (int n2l = 0; n2l < 25; ++n2l) {
      float4 e = pe[n2l];
      re += e.z * c; im += e.w * c;
      c = -c;
    }
    spec[sig * FS + 5000u] = make_float2(re, im);
  }
}

// ---------------- mix: b-tile 8, k-chunk 64, 4-way s-split; grid (80,8) = 640 blocks ----------------
__global__ __launch_bounds__(256) void k_mix(const float2* __restrict__ spec,
                      const float* __restrict__ tmask, const float* __restrict__ rmask,
                      const int* __restrict__ aidx, const int* __restrict__ rpos,
                      float2* __restrict__ G) {
  __shared__ float2 FaS[10][64];
  __shared__ float2 FcS[64];
  __shared__ float tmS[8][128];
  __shared__ int   aiS[8][128];
  __shared__ float rmS[8][8];
  __shared__ int   rpS[8][8][2];
  __shared__ float2 red[4][8][64];
  int tid = threadIdx.x;
  int kl = tid & 63, grp = tid >> 6;
  int k = blockIdx.x * 64 + kl;
  int kc = k > 5000 ? 5000 : k;
  int b0 = blockIdx.y * 8;
  for (int i = tid; i < 640; i += 256) {
    int a = i >> 6, kk = i & 63;
    int kg = blockIdx.x * 64 + kk; if (kg > 5000) kg = 5000;
    FaS[a][kk] = spec[(128 + a) * FS + kg];
  }
  if (tid < 64) FcS[tid] = spec[138 * FS + kc];
  for (int i = tid; i < 8 * 128; i += 256) {
    int bb = i >> 7, ss = i & 127;
    tmS[bb][ss] = tmask[(b0 + bb) * 128 + ss];
    aiS[bb][ss] = aidx[(b0 + bb) * 128 + ss];
  }
  if (tid < 64) {
    int bb = tid >> 3, rr = tid & 7;
    rmS[bb][rr] = rmask[(b0 + bb) * 8 + rr];
    rpS[bb][rr][0] = rpos[((b0 + bb) * 8 + rr) * 2 + 0];
    rpS[bb][rr][1] = rpos[((b0 + bb) * 8 + rr) * 2 + 1];
  }
  __syncthreads();
  float fr[8] = {}, fi[8] = {};
  int sbase = grp * 32;
#pragma unroll 4
  for (int si = 0; si < 32; ++si) {
    int s = sbase + si;
    float2 fp = spec[s * FS + kc];
#pragma unroll
    for (int b = 0; b < 8; ++b) {
      int a = aiS[b][s];
      float tm = tmS[b][s];
      float2 fa = FaS[a][kl];
      fr[b] += tm * (fa.x * fp.x - fa.y * fp.y);
      fi[b] += tm * (fa.x * fp.y + fa.y * fp.x);
    }
  }
  float2 fc = FcS[kl];
#pragma unroll
  for (int rr = 0; rr < 2; ++rr) {
    int r = grp * 2 + rr;
#pragma unroll
    for (int b = 0; b < 8; ++b) {
      int p0 = rpS[b][r][0], p1 = rpS[b][r][1];
      float rm = rmS[b][r];
      float2 f0 = spec[p0 * FS + kc];
      float2 f1 = spec[p1 * FS + kc];
      float tr = f0.x * f1.x - f0.y * f1.y;
      float ti = f0.x * f1.y + f0.y * f1.x;
      fr[b] += rm * (tr * fc.x - ti * fc.y);
      fi[b] += rm * (tr * fc.y + ti * fc.x);
    }
  }
#pragma unroll
  for (int b = 0; b < 8; ++b) red[grp][b][kl] = make_float2(fr[b], fi[b]);
  __syncthreads();
#pragma unroll
  for (int j = 0; j < 2; ++j) {
    int slot = j * 256 + tid;
    int b = slot >> 6, kk = slot & 63;
    int kg = blockIdx.x * 64 + kk;
    if (kg <= 5000) {
      float R = red[0][b][kk].x + red[1][b][kk].x + red[2][b][kk].x + red[3][b][kk].x;
      float I = red[0][b][kk].y + red[1][b][kk].y + red[2][b][kk].y + red[3][b][kk].y;
      if (kg == 0 || kg == 5000) I = 0.0f;   // exact Hermitian guard
      G[(size_t)(b0 + b) * 10000 + kg] = make_float2(R, I);
      if (kg >= 1 && kg <= 4999)
        G[(size_t)(b0 + b) * 10000 + (10000 - kg)] = make_float2(R, -I);
    }
  }
}

// ---------------- inverse stage 1: radix-4 folded + (m1, m1+50) pairing ----------------
__global__ __launch_bounds__(256) void k_i1(const float2* __restrict__ G,
                                            float2* __restrict__ Bi) {
  __shared__ float lds[10400];   // 4 tables x [25][26] float4 = 41.6 KB
  unsigned sig = blockIdx.x;
  const float* gp = (const float*)(G + sig * 10000u);
  int tid = threadIdx.x;
  float* c0v = lds;          // {C0.re(n2), C0.im(n2), C0.re(n2+1), C0.im(n2+1)}
  float* c2v = lds + 2600;
  float* cpr = lds + 5200;   // {P, R, P', R'}
  float* cqt = lds + 7800;   // {Q, T, Q', T'}
  for (int t2 = tid; t2 < 650; t2 += 256) {
    const float* p = gp + (t2 / 26) * 200 + (t2 % 26) * 4;
    float4 g0 = *(const float4*)(p);
    float4 g1 = *(const float4*)(p + 5000);
    float4 g2 = *(const float4*)(p + 10000);
    float4 g3 = *(const float4*)(p + 15000);
    float4 a, b, pr, qt;
    a.x = (g0.x + g2.x) + (g1.x + g3.x);
    a.y = (g0.y + g2.y) + (g1.y + g3.y);
    a.z = (g0.z + g2.z) + (g1.z + g3.z);
    a.w = (g0.w + g2.w) + (g1.w + g3.w);
    b.x = (g0.x + g2.x) - (g1.x + g3.x);
    b.y = (g0.y + g2.y) - (g1.y + g3.y);
    b.z = (g0.z + g2.z) - (g1.z + g3.z);
    b.w = (g0.w + g2.w) - (g1.w + g3.w);
    pr.x = g0.x - g2.x;  pr.y = g0.y - g2.y;
    pr.z = g0.z - g2.z;  pr.w = g0.w - g2.w;
    qt.x = g1.y - g3.y;  qt.y = g1.x - g3.x;
    qt.z = g1.w - g3.w;  qt.w = g1.z - g3.z;
    *(float4*)(c0v + t2 * 4) = a;
    *(float4*)(c2v + t2 * 4) = b;
    *(float4*)(cpr + t2 * 4) = pr;
    *(float4*)(cqt + t2 * 4) = qt;
  }
  __syncthreads();
  unsigned t = blockIdx.y * 256u + tid;
  if (t >= 1300u) return;
  unsigned m1 = t / 26u, n2p = t % 26u, n2 = n2p * 2u;   // m1 in [0,50)
  float cth, sth;
  __sincosf(PI2 * (float)m1 * 0.01f, &sth, &cth);
  unsigned m = m1 & 3u;
  const float4* pe  = (const float4*)((m == 0u) ? c0v : (m == 2u) ? c2v : cpr) + n2p;
  const float4* pe2 = (const float4*)((m == 0u) ? c2v : (m == 2u) ? c0v : cpr) + n2p;
  const float4* pq  = (const float4*)cqt + n2p;
  float qmul = (m == 1u) ? -1.0f : (m == 3u) ? 1.0f : 0.0f;
  float qmul2 = -qmul;
  float c = 1.0f, s = 0.0f, sg = 1.0f;
  float reA = 0.f, imA = 0.f, reB = 0.f, imB = 0.f;
  float reA2 = 0.f, imA2 = 0.f, reB2 = 0.f, imB2 = 0.f;
#pragma unroll 5
  for (int n1l = 0; n1l < 25; ++n1l) {
    float4 ev = pe[n1l * 26];
    float4 e2 = pe2[n1l * 26];
    float4 qv = pq[n1l * 26];
    float gx = ev.x + qmul * qv.x,  gy = ev.y - qmul * qv.y;
    float gz = ev.z + qmul * qv.z,  gw = ev.w - qmul * qv.w;
    float hx = e2.x + qmul2 * qv.x, hy = e2.y - qmul2 * qv.y;
    float hz = e2.z + qmul2 * qv.z, hw = e2.w - qmul2 * qv.w;
    reA += gx * c - gy * s;  imA += gy * c + gx * s;
    reB += gz * c - gw * s;  imB += gw * c + gz * s;
    float cs = sg * c, ss = sg * s;
    reA2 += hx * cs - hy * ss;  imA2 += hy * cs + hx * ss;
    reB2 += hz * cs - hw * ss;  imB2 += hw * cs + hz * ss;
    float cn = c * cth - s * sth;
    float sn = s * cth + c * sth;
    c = cn; s = sn; sg = -sg;
  }
  float w0 = (n2 == 0u || n2 == 50u) ? 0.5f : 1.0f;
  float w1 = (n2 == 50u) ? 0.0f : 1.0f;   // col 51 unused
  {
    float sw0, cw0, sw1, cw1;
    __sincosf(PI2 * (float)(n2 * m1) * 1e-4f, &sw0, &cw0);
    __sincosf(PI2 * (float)((n2 + 1u) * m1) * 1e-4f, &sw1, &cw1);
    float4 outv;
    outv.x = (reA * cw0 - imA * sw0) * w0;
    outv.y = (imA * cw0 + reA * sw0) * w0;
    outv.z = (reB * cw1 - imB * sw1) * w1;
    outv.w = (imB * cw1 + reB * sw1) * w1;
    *(float4*)((float*)Bi + (sig * 5200u + m1 * 52u + n2) * 2) = outv;
  }
  {
    unsigned m1b = m1 + 50u;
    float sw0, cw0, sw1, cw1;
    __sincosf(PI2 * (float)(n2 * m1b) * 1e-4f, &sw0, &cw0);
    __sincosf(PI2 * (float)((n2 + 1u) * m1b) * 1e-4f, &sw1, &cw1);
    float4 outv;
    outv.x = (reA2 * cw0 - imA2 * sw0) * w0;
    outv.y = (imA2 * cw0 + reA2 * sw0) * w0;
    outv.z = (reB2 * cw1 - imB2 * sw1) * w1;
    outv.w = (imB2 * cw1 + reB2 * sw1) * w1;
    *(float4*)((float*)Bi + (sig * 5200u + m1b * 52u + n2) * 2) = outv;
  }
}

// ---------------- inverse stage 2: (m2, m2+50) pairing, LDS-transposed coalesced mol write ----------------
__global__ __launch_bounds__(640) void k_i2(const float2* __restrict__ Bi,
                                            float* __restrict__ mol) {
  __shared__ float ls[100 * 26];   // [m2][m1l] padded-26 (10.4 KB)
  unsigned sig = blockIdx.x, q = blockIdx.y;
  int tid = threadIdx.x;
  if (tid < 625) {
    unsigned m1l = (unsigned)tid / 25u;   // 0..24
    unsigned m2 = ((unsigned)tid % 25u) * 2u;  // 0..48 even
    const float* bp = (const float*)Bi + sig * 10400u + q * 2600u + m1l * 104u;
    float cthA, sthA, cthB, sthB;
    __sincosf(PI2 * (float)m2 * 0.01f, &sthA, &cthA);
    __sincosf(PI2 * (float)(m2 + 1u) * 0.01f, &sthB, &cthB);
    float cA = 1.0f, sA = 0.0f, cB = 1.0f, sB = 0.0f;
    float r0e = 0.f, r0o = 0.f, r1e = 0.f, r1o = 0.f;
#pragma unroll 4
    for (int jj = 0; jj < 26; ++jj) {
      const float4 v0 = *(const float4*)(bp + 4 * jj);
      r0e += v0.x * cA - v0.y * sA;      // n2 even
      r1e += v0.x * cB - v0.y * sB;
      float cA1 = cA * cthA - sA * sthA, sA1 = sA * cthA + cA * sthA;
      float cB1 = cB * cthB - sB * sthB, sB1 = sB * cthB + cB * sthB;
      r0o += v0.z * cA1 - v0.w * sA1;    // n2 odd
      r1o += v0.z * cB1 - v0.w * sB1;
      cA = cA1 * cthA - sA1 * sthA; sA = sA1 * cthA + cA1 * sthA;
      cB = cB1 * cthB - sB1 * sthB; sB = sB1 * cthB + cB1 * sthB;
    }
    ls[m2 * 26 + m1l]          = (r0e + r0o) * 2e-4f;
    ls[(m2 + 1u) * 26 + m1l]   = (r1e + r1o) * 2e-4f;
    ls[(m2 + 50u) * 26 + m1l]  = (r0e - r0o) * 2e-4f;
    ls[(m2 + 51u) * 26 + m1l]  = (r1e - r1o) * 2e-4f;
  }
  __syncthreads();
  float* mp = mol + sig * 10000u + q * 25u;
  for (int i = tid; i < 2500; i += 640) {
    int m2 = i / 25, m1l = i % 25;
    mp[100 * m2 + m1l] = ls[m2 * 26 + m1l];
  }
}

// ---------------- projection: float4 compute (1 spread + 2 broadcast b128 per dl) ----------------
__global__ __launch_bounds__(512) void k_proj(const float* __restrict__ mol,
                                              const float* __restrict__ W,
                                              float* __restrict__ part) {
  __shared__ float molS[40 * 68];      // [dl][b], pad 68 (16B-aligned rows)
  __shared__ float WS[40][260];        // [dl][p], pad 260 (16B-aligned rows)
  int tid = threadIdx.x;
  int d0 = blockIdx.x * 40;
  for (int i = tid; i < 40 * 64; i += 512) {
    int b = i / 40, dl = i % 40;
    molS[dl * 68 + b] = mol[(size_t)b * 10000 + d0 + dl];
  }
  for (int i = tid; i < 40 * 256; i += 512) {
    int p = i / 40, dl = i % 40;
    WS[dl][p] = W[(size_t)p * 10000 + d0 + dl];
  }
  __syncthreads();
  int p0 = (tid & 63) * 4;
  int bh = (tid >> 6) * 8;
  float acc[4][8] = {};
#pragma unroll 4
  for (int dl = 0; dl < 40; ++dl) {
    const float4 wv = *(const float4*)(&WS[dl][p0]);
    const float4 m0 = *(const float4*)(molS + dl * 68 + bh);
    const float4 m1 = *(const float4*)(molS + dl * 68 + bh + 4);
#pragma unroll
    for (int j = 0; j < 4; ++j) {
      float w = (j == 0) ? wv.x : (j == 1) ? wv.y : (j == 2) ? wv.z : wv.w;
      acc[j][0] += w * m0.x;  acc[j][1] += w * m0.y;
      acc[j][2] += w * m0.z;  acc[j][3] += w * m0.w;
      acc[j][4] += w * m1.x;  acc[j][5] += w * m1.y;
      acc[j][6] += w * m1.z;  acc[j][7] += w * m1.w;
    }
  }
#pragma unroll
  for (int b = 0; b < 8; ++b) {
    float4 v = make_float4(acc[0][b], acc[1][b], acc[2][b], acc[3][b]);
    *(float4*)(part + (size_t)blockIdx.x * 16384 + (bh + b) * 256 + p0) = v;
  }
}

// ---------------- reduce partials + bias ----------------
__global__ __launch_bounds__(256) void k_red(const float* __restrict__ part,
                                             const float* __restrict__ bias,
                                             float* __restrict__ out) {
  __shared__ float red[4][64];
  int tid = threadIdx.x;
  int pl = tid & 63, cg = tid >> 6;
  int b = blockIdx.x;
  int p = blockIdx.y * 64 + pl;
  float acc = 0.0f;
#pragma unroll 8
  for (int ch = cg; ch < 250; ch += 4)
    acc += part[(size_t)ch * 16384 + b * 256 + p];
  red[cg][pl] = acc;
  __syncthreads();
  if (tid < 64)
    out[b * 256 + p] = red[0][pl] + red[1][pl] + red[2][pl] + red[3][pl] + bias[p];
}

extern "C" void kernel_launch(void* const* d_in, const int* in_sizes, int n_in,
                              void* d_out, int out_size, void* d_ws, size_t ws_size,
                              hipStream_t stream) {
  const float* atom  = (const float*)d_in[0];   // [10,10000]
  const float* pos   = (const float*)d_in[1];   // [128,10000]
  const float* clo   = (const float*)d_in[2];   // [10000]
  const float* W     = (const float*)d_in[3];   // [256,10000]
  const float* bias  = (const float*)d_in[4];   // [256]
  const float* tmask = (const float*)d_in[5];   // [64,128]
  const float* rmask = (const float*)d_in[6];   // [64,8]
  const int*   aidx  = (const int*)d_in[7];     // [64,128]
  const int*   rpos  = (const int*)d_in[8];     // [64,8,2]
  float* out = (float*)d_out;                   // [64,256]

  char* ws = (char*)d_ws;
  size_t off = 0;
  auto alloc = [&](size_t n) { off = (off + 255) & ~(size_t)255; size_t o = off; off += n; return o; };
  char* regA   = ws + alloc(16777216);          // Bi (2.66MB) / partials (16.4MB)
  float2* Bi   = (float2*)regA;                 // i1/i2 use Bi before proj writes part
  float*  part = (float*)regA;
  float2* spec = (float2*)(ws + alloc((size_t)NSIG * FS * 8));
  float2* G    = (float2*)(ws + alloc((size_t)64 * 10000 * 8));
  float*  mol  = (float*)(ws + alloc((size_t)64 * 10000 * 4));

  k_fwd<<<dim3(NSIG, 6), dim3(256), 0, stream>>>(atom, pos, clo, spec);
  k_mix<<<dim3(80, 8), dim3(256), 0, stream>>>(spec, tmask, rmask, aidx, rpos, G);
  k_i1<<<dim3(64, 6), dim3(256), 0, stream>>>(G, Bi);
  k_i2<<<dim3(64, 4), dim3(640), 0, stream>>>(Bi, mol);
  k_proj<<<dim3(250), dim3(512), 0, stream>>>(mol, W, part);
  k_red<<<dim3(64, 4), dim3(256), 0, stream>>>(part, bias, out);
}

// Round 7
// 156.015 us; speedup vs baseline: 1.2246x; 1.0168x over previous
//
#include <hip/hip_runtime.h>

#define PI2 6.28318530717958647692f

// D = 10000 = 100 x 100; F = 5001; signals: 128 pos + 10 atom + 1 closure = 139
#define NSIG 139
#define FS   5120      // spectrum row stride (float2)

// ---------------- fused forward (f1+f2), Hermitian-paired, radix-4 folded ----------------
// 51 = 3 x 17: grid (139,3), 512 threads, nk1=17 -> fold computed 3x/sig instead of 6x,
// no near-empty tail block, ntile1=425 single uniform round.
__global__ __launch_bounds__(512) void k_fwd(
                     const float* __restrict__ atom, const float* __restrict__ pos,
                     const float* __restrict__ clo, float2* __restrict__ spec) {
  __shared__ float lds[13600];   // 54.4 KB union: phase1 tables (10000) / xs(6800)+cse/cso(6800)
  unsigned sig = blockIdx.x, q = blockIdx.y;
  unsigned k1base = q * 17u;
  unsigned nk1 = 17u;
  const float* xb = (sig < 128u) ? (pos + sig * 10000u)
                   : ((sig < 138u) ? (atom + (sig - 128u) * 10000u) : clo);
  int tid = threadIdx.x;

  // ---- phase 1a: radix-4 fold of x ----
  {
    float* csA = lds;
    float* csB = lds + 2500;
    float* csG = lds + 5000;
    float* csH = lds + 7500;
    for (int t2 = tid; t2 < 625; t2 += 512) {
      const float* p = xb + (t2 / 25) * 100 + (t2 % 25) * 4;
      float4 x0 = *(const float4*)(p);
      float4 x1 = *(const float4*)(p + 2500);
      float4 x2 = *(const float4*)(p + 5000);
      float4 x3 = *(const float4*)(p + 7500);
      float4 A, B, G, H;
      A.x = (x0.x + x2.x) + (x1.x + x3.x);
      A.y = (x0.y + x2.y) + (x1.y + x3.y);
      A.z = (x0.z + x2.z) + (x1.z + x3.z);
      A.w = (x0.w + x2.w) + (x1.w + x3.w);
      B.x = (x0.x + x2.x) - (x1.x + x3.x);
      B.y = (x0.y + x2.y) - (x1.y + x3.y);
      B.z = (x0.z + x2.z) - (x1.z + x3.z);
      B.w = (x0.w + x2.w) - (x1.w + x3.w);
      G.x = x0.x - x2.x;  G.y = x0.y - x2.y;
      G.z = x0.z - x2.z;  G.w = x0.w - x2.w;
      H.x = x1.x - x3.x;  H.y = x1.y - x3.y;
      H.z = x1.z - x3.z;  H.w = x1.w - x3.w;
      *(float4*)(csA + t2 * 4) = A;
      *(float4*)(csB + t2 * 4) = B;
      *(float4*)(csG + t2 * 4) = G;
      *(float4*)(csH + t2 * 4) = H;
    }
  }
  __syncthreads();

  // ---- phase 1b: 25-iter folded DFT + phase-2 twiddles ----
  unsigned ntile1 = nk1 * 25u;   // 425
  unsigned k1l = tid / 25u, n2q = (unsigned)tid % 25u, n2 = n2q * 4u;
  bool have = (unsigned)tid < ntile1;
  unsigned k1 = k1base + k1l;
  float resA[8], resB[8];
  if (have) {
    float cth, sth;
    __sincosf(PI2 * (float)k1 * 0.01f, &sth, &cth);
    unsigned m = k1 & 3u;
    const float4* creP = (const float4*)((m == 0u) ? lds
                          : (m == 2u) ? (lds + 2500) : (lds + 5000)) + n2q;
    const float4* cimP = (const float4*)(lds + 7500) + n2q;
    float im_mul = (m == 1u) ? 1.0f : (m == 3u) ? -1.0f : 0.0f;
    float c = 1.0f, s = 0.0f;
    float ar[4] = {}, as[4] = {};
#pragma unroll 5
    for (int n1l = 0; n1l < 25; ++n1l) {
      float4 Cre = creP[n1l * 25];
      float4 Cim = cimP[n1l * 25];
      float se = im_mul * s, ce = im_mul * c;
      ar[0] += Cre.x * c - Cim.x * se;  as[0] += Cim.x * ce + Cre.x * s;
      ar[1] += Cre.y * c - Cim.y * se;  as[1] += Cim.y * ce + Cre.y * s;
      ar[2] += Cre.z * c - Cim.z * se;  as[2] += Cim.z * ce + Cre.z * s;
      ar[3] += Cre.w * c - Cim.w * se;  as[3] += Cim.w * ce + Cre.w * s;
      float cn = c * cth - s * sth;
      float sn = s * cth + c * sth;
      c = cn; s = sn;
    }
    unsigned rb = (100u - k1) % 100u;
#pragma unroll
    for (int j = 0; j < 4; ++j) {
      float swA, cwA, swB, cwB;
      __sincosf(PI2 * (float)((n2 + j) * k1) * 1e-4f, &swA, &cwA);
      __sincosf(PI2 * (float)((n2 + j) * rb) * 1e-4f, &swB, &cwB);
      resA[2 * j + 0] = ar[j] * cwA - as[j] * swA;
      resA[2 * j + 1] = -(as[j] * cwA + ar[j] * swA);
      resB[2 * j + 0] = ar[j] * cwB + as[j] * swB;
      resB[2 * j + 1] = as[j] * cwB - ar[j] * swB;
    }
  }
  __syncthreads();   // phase-1 tables dead; lds reused as xs below
  float* xs = lds;   // nrow x 200 floats (34 x 200 = 6800)
  if (have) {
    float* pA = xs + k1l * 200u + n2 * 2u;
    float* pB = xs + (nk1 + k1l) * 200u + n2 * 2u;
    *(float4*)(pA + 0) = make_float4(resA[0], resA[1], resA[2], resA[3]);
    *(float4*)(pA + 4) = make_float4(resA[4], resA[5], resA[6], resA[7]);
    *(float4*)(pB + 0) = make_float4(resB[0], resB[1], resB[2], resB[3]);
    *(float4*)(pB + 4) = make_float4(resB[4], resB[5], resB[6], resB[7]);
  }
  __syncthreads();

  // ---- phase 3a: radix-4 fold of the complex rows (e^{-i} direction) ----
  unsigned nrow = 2u * nk1;      // 34
  float* cse = lds + 6800;
  float* cso = lds + 10200;
  for (int t3 = tid; t3 < (int)(nrow * 25u); t3 += 512) {
    const float* br = xs + (t3 / 25) * 200;
    int n2l = t3 % 25;
    float2 b0 = *(const float2*)(br + 2 * n2l);
    float2 b1 = *(const float2*)(br + 2 * (25 + n2l));
    float2 b2 = *(const float2*)(br + 2 * (50 + n2l));
    float2 b3 = *(const float2*)(br + 2 * (75 + n2l));
    float4 e, o;
    e.x = (b0.x + b2.x) + (b1.x + b3.x);
    e.y = (b0.y + b2.y) + (b1.y + b3.y);
    e.z = (b0.x + b2.x) - (b1.x + b3.x);
    e.w = (b0.y + b2.y) - (b1.y + b3.y);
    o.x = b0.x - b2.x;   // P
    o.y = b1.y - b3.y;   // Q
    o.z = b0.y - b2.y;   // R
    o.w = b1.x - b3.x;   // T
    *(float4*)(cse + t3 * 4) = e;
    *(float4*)(cso + t3 * 4) = o;
  }
  __syncthreads();

  // ---- phase 3b: 25 uniform k2-pairs (k2 <= 48); stores unconditional ----
  unsigned ntile3 = nrow * 25u;  // 850
  for (unsigned t = tid; t < ntile3; t += 512u) {
    unsigned lr = t / 25u, k2 = (t % 25u) * 2u;
    unsigned gk1 = (lr < nk1) ? (k1base + lr) : ((100u - (k1base + (lr - nk1))) % 100u);
    float cthA, sthA, cthB, sthB;
    __sincosf(PI2 * (float)k2 * 0.01f, &sthA, &cthA);
    __sincosf(PI2 * (float)(k2 + 1) * 0.01f, &sthB, &cthB);
    bool hi = (k2 & 2u) != 0u;
    float sq = hi ? -1.0f : 1.0f;
    const float4* pe = (const float4*)(cse + lr * 100);
    const float4* po = (const float4*)(cso + lr * 100);
    float cA = 1.0f, sA = 0.0f, cB = 1.0f, sB = 0.0f;
    float reA = 0.f, imA = 0.f, reB = 0.f, imB = 0.f;
#pragma unroll 5
    for (int n2l = 0; n2l < 25; ++n2l) {
      float4 e = pe[n2l];
      float4 o = po[n2l];
      float car = hi ? e.z : e.x;
      float cai = hi ? e.w : e.y;
      float cbr = o.x + sq * o.y;
      float cbi = o.z - sq * o.w;
      reA += car * cA + cai * sA;  imA += cai * cA - car * sA;
      reB += cbr * cB + cbi * sB;  imB += cbi * cB - cbr * sB;
      float cA1 = cA * cthA - sA * sthA, sA1 = sA * cthA + cA * sthA;
      float cB1 = cB * cthB - sB * sthB, sB1 = sB * cthB + cB * sthB;
      cA = cA1; sA = sA1; cB = cB1; sB = sB1;
    }
    unsigned kA = gk1 + 100u * k2;
    spec[sig * FS + kA] = make_float2(reA, imA);
    spec[sig * FS + kA + 100u] = make_float2(reB, imB);
  }
  // k2 = 50: only gk1 = 0 survives (kA = 5000); hi=true table, twiddle (-1)^n2l
  if (k1base == 0u && tid == 255) {
    const float4* pe = (const float4*)(cse);   // lr = 0 (gk1 = 0)
    float c = 1.0f, re = 0.f, im = 0.f;
#pragma unroll 5
    for (int n2l = 0; n2l < 25; ++n2l) {
      float4 e = pe[n2l];
      re += e.z * c; im += e.w * c;
      c = -c;
    }
    spec[sig * FS + 5000u] = make_float2(re, im);
  }
}

// ---------------- mix: b-tile 16, k-chunk 64, 4-way s-split; grid (80,4) = 320 blocks ----------------
// Spec s-loop traffic 21 MB (half of b8); ai/tm packed [s][16] for int4/float4 broadcast reads.
__global__ __launch_bounds__(256) void k_mix(const float2* __restrict__ spec,
                      const float* __restrict__ tmask, const float* __restrict__ rmask,
                      const int* __restrict__ aidx, const int* __restrict__ rpos,
                      float2* __restrict__ G) {
  __shared__ float2 FaS[10][64];
  __shared__ float2 FcS[64];
  __shared__ float tmS[128][16];
  __shared__ int   aiS[128][16];
  __shared__ float rmS[16][8];
  __shared__ int   rpS[16][8][2];
  __shared__ float2 red[4][16][64];
  int tid = threadIdx.x;
  int kl = tid & 63, grp = tid >> 6;
  int k = blockIdx.x * 64 + kl;
  int kc = k > 5000 ? 5000 : k;
  int b0 = blockIdx.y * 16;
  for (int i = tid; i < 640; i += 256) {
    int a = i >> 6, kk = i & 63;
    int kg = blockIdx.x * 64 + kk; if (kg > 5000) kg = 5000;
    FaS[a][kk] = spec[(128 + a) * FS + kg];
  }
  if (tid < 64) FcS[tid] = spec[138 * FS + kc];
  for (int i = tid; i < 16 * 128; i += 256) {
    int bb = i >> 7, ss = i & 127;
    tmS[ss][bb] = tmask[(b0 + bb) * 128 + ss];
    aiS[ss][bb] = aidx[(b0 + bb) * 128 + ss];
  }
  if (tid < 128) {
    int bb = tid >> 3, rr = tid & 7;
    rmS[bb][rr] = rmask[(b0 + bb) * 8 + rr];
    rpS[bb][rr][0] = rpos[((b0 + bb) * 8 + rr) * 2 + 0];
    rpS[bb][rr][1] = rpos[((b0 + bb) * 8 + rr) * 2 + 1];
  }
  __syncthreads();
  float fr[16] = {}, fi[16] = {};
  int sbase = grp * 32;
#pragma unroll 2
  for (int si = 0; si < 32; ++si) {
    int s = sbase + si;
    float2 fp = spec[s * FS + kc];
#pragma unroll
    for (int bq = 0; bq < 4; ++bq) {
      const int4  ai4 = *(const int4*)(&aiS[s][bq * 4]);
      const float4 tm4 = *(const float4*)(&tmS[s][bq * 4]);
#pragma unroll
      for (int bj = 0; bj < 4; ++bj) {
        int b = bq * 4 + bj;
        int a = (bj == 0) ? ai4.x : (bj == 1) ? ai4.y : (bj == 2) ? ai4.z : ai4.w;
        float tm = (bj == 0) ? tm4.x : (bj == 1) ? tm4.y : (bj == 2) ? tm4.z : tm4.w;
        float2 fa = FaS[a][kl];
        fr[b] += tm * (fa.x * fp.x - fa.y * fp.y);
        fi[b] += tm * (fa.x * fp.y + fa.y * fp.x);
      }
    }
  }
  float2 fc = FcS[kl];
#pragma unroll
  for (int rr = 0; rr < 2; ++rr) {
    int r = grp * 2 + rr;
#pragma unroll
    for (int b = 0; b < 16; ++b) {
      int p0 = rpS[b][r][0], p1 = rpS[b][r][1];
      float rm = rmS[b][r];
      float2 f0 = spec[p0 * FS + kc];
      float2 f1 = spec[p1 * FS + kc];
      float tr = f0.x * f1.x - f0.y * f1.y;
      float ti = f0.x * f1.y + f0.y * f1.x;
      fr[b] += rm * (tr * fc.x - ti * fc.y);
      fi[b] += rm * (tr * fc.y + ti * fc.x);
    }
  }
#pragma unroll
  for (int b = 0; b < 16; ++b) red[grp][b][kl] = make_float2(fr[b], fi[b]);
  __syncthreads();
#pragma unroll
  for (int j = 0; j < 4; ++j) {
    int slot = j * 256 + tid;
    int b = slot >> 6, kk = slot & 63;
    int kg = blockIdx.x * 64 + kk;
    if (kg <= 5000) {
      float R = red[0][b][kk].x + red[1][b][kk].x + red[2][b][kk].x + red[3][b][kk].x;
      float I = red[0][b][kk].y + red[1][b][kk].y + red[2][b][kk].y + red[3][b][kk].y;
      if (kg == 0 || kg == 5000) I = 0.0f;   // exact Hermitian guard
      G[(size_t)(b0 + b) * 10000 + kg] = make_float2(R, I);
      if (kg >= 1 && kg <= 4999)
        G[(size_t)(b0 + b) * 10000 + (10000 - kg)] = make_float2(R, -I);
    }
  }
}

// ---------------- inverse stage 1: radix-4 folded + (m1, m1+50) pairing; grid (64,3) x 512 ----------------
__global__ __launch_bounds__(512) void k_i1(const float2* __restrict__ G,
                                            float2* __restrict__ Bi) {
  __shared__ float lds[10400];   // 4 tables x [25][26] float4 = 41.6 KB
  unsigned sig = blockIdx.x;
  const float* gp = (const float*)(G + sig * 10000u);
  int tid = threadIdx.x;
  float* c0v = lds;          // {C0.re(n2), C0.im(n2), C0.re(n2+1), C0.im(n2+1)}
  float* c2v = lds + 2600;
  float* cpr = lds + 5200;   // {P, R, P', R'}
  float* cqt = lds + 7800;   // {Q, T, Q', T'}
  for (int t2 = tid; t2 < 650; t2 += 512) {
    const float* p = gp + (t2 / 26) * 200 + (t2 % 26) * 4;
    float4 g0 = *(const float4*)(p);
    float4 g1 = *(const float4*)(p + 5000);
    float4 g2 = *(const float4*)(p + 10000);
    float4 g3 = *(const float4*)(p + 15000);
    float4 a, b, pr, qt;
    a.x = (g0.x + g2.x) + (g1.x + g3.x);
    a.y = (g0.y + g2.y) + (g1.y + g3.y);
    a.z = (g0.z + g2.z) + (g1.z + g3.z);
    a.w = (g0.w + g2.w) + (g1.w + g3.w);
    b.x = (g0.x + g2.x) - (g1.x + g3.x);
    b.y = (g0.y + g2.y) - (g1.y + g3.y);
    b.z = (g0.z + g2.z) - (g1.z + g3.z);
    b.w = (g0.w + g2.w) - (g1.w + g3.w);
    pr.x = g0.x - g2.x;  pr.y = g0.y - g2.y;
    pr.z = g0.z - g2.z;  pr.w = g0.w - g2.w;
    qt.x = g1.y - g3.y;  qt.y = g1.x - g3.x;
    qt.z = g1.w - g3.w;  qt.w = g1.z - g3.z;
    *(float4*)(c0v + t2 * 4) = a;
    *(float4*)(c2v + t2 * 4) = b;
    *(float4*)(cpr + t2 * 4) = pr;
    *(float4*)(cqt + t2 * 4) = qt;
  }
  __syncthreads();
  unsigned t = blockIdx.y * 512u + tid;
  if (t >= 1300u) return;
  unsigned m1 = t / 26u, n2p = t % 26u, n2 = n2p * 2u;   // m1 in [0,50)
  float cth, sth;
  __sincosf(PI2 * (float)m1 * 0.01f, &sth, &cth);
  unsigned m = m1 & 3u;
  const float4* pe  = (const float4*)((m == 0u) ? c0v : (m == 2u) ? c2v : cpr) + n2p;
  const float4* pe2 = (const float4*)((m == 0u) ? c2v : (m == 2u) ? c0v : cpr) + n2p;
  const float4* pq  = (const float4*)cqt + n2p;
  float qmul = (m == 1u) ? -1.0f : (m == 3u) ? 1.0f : 0.0f;
  float qmul2 = -qmul;
  float c = 1.0f, s = 0.0f, sg = 1.0f;
  float reA = 0.f, imA = 0.f, reB = 0.f, imB = 0.f;
  float reA2 = 0.f, imA2 = 0.f, reB2 = 0.f, imB2 = 0.f;
#pragma unroll 5
  for (int n1l = 0; n1l < 25; ++n1l) {
    float4 ev = pe[n1l * 26];
    float4 e2 = pe2[n1l * 26];
    float4 qv = pq[n1l * 26];
    float gx = ev.x + qmul * qv.x,  gy = ev.y - qmul * qv.y;
    float gz = ev.z + qmul * qv.z,  gw = ev.w - qmul * qv.w;
    float hx = e2.x + qmul2 * qv.x, hy = e2.y - qmul2 * qv.y;
    float hz = e2.z + qmul2 * qv.z, hw = e2.w - qmul2 * qv.w;
    reA += gx * c - gy * s;  imA += gy * c + gx * s;
    reB += gz * c - gw * s;  imB += gw * c + gz * s;
    float cs = sg * c, ss = sg * s;
    reA2 += hx * cs - hy * ss;  imA2 += hy * cs + hx * ss;
    reB2 += hz * cs - hw * ss;  imB2 += hw * cs + hz * ss;
    float cn = c * cth - s * sth;
    float sn = s * cth + c * sth;
    c = cn; s = sn; sg = -sg;
  }
  float w0 = (n2 == 0u || n2 == 50u) ? 0.5f : 1.0f;
  float w1 = (n2 == 50u) ? 0.0f : 1.0f;   // col 51 unused
  {
    float sw0, cw0, sw1, cw1;
    __sincosf(PI2 * (float)(n2 * m1) * 1e-4f, &sw0, &cw0);
    __sincosf(PI2 * (float)((n2 + 1u) * m1) * 1e-4f, &sw1, &cw1);
    float4 outv;
    outv.x = (reA * cw0 - imA * sw0) * w0;
    outv.y = (imA * cw0 + reA * sw0) * w0;
    outv.z = (reB * cw1 - imB * sw1) * w1;
    outv.w = (imB * cw1 + reB * sw1) * w1;
    *(float4*)((float*)Bi + (sig * 5200u + m1 * 52u + n2) * 2) = outv;
  }
  {
    unsigned m1b = m1 + 50u;
    float sw0, cw0, sw1, cw1;
    __sincosf(PI2 * (float)(n2 * m1b) * 1e-4f, &sw0, &cw0);
    __sincosf(PI2 * (float)((n2 + 1u) * m1b) * 1e-4f, &sw1, &cw1);
    float4 outv;
    outv.x = (reA2 * cw0 - imA2 * sw0) * w0;
    outv.y = (imA2 * cw0 + reA2 * sw0) * w0;
    outv.z = (reB2 * cw1 - imB2 * sw1) * w1;
    outv.w = (imB2 * cw1 + reB2 * sw1) * w1;
    *(float4*)((float*)Bi + (sig * 5200u + m1b * 52u + n2) * 2) = outv;
  }
}

// ---------------- inverse stage 2: (m2, m2+50) pairing, LDS-transposed coalesced mol write ----------------
__global__ __launch_bounds__(640) void k_i2(const float2* __restrict__ Bi,
                                            float* __restrict__ mol) {
  __shared__ float ls[100 * 26];   // [m2][m1l] padded-26 (10.4 KB)
  unsigned sig = blockIdx.x, q = blockIdx.y;
  int tid = threadIdx.x;
  if (tid < 625) {
    unsigned m1l = (unsigned)tid / 25u;   // 0..24
    unsigned m2 = ((unsigned)tid % 25u) * 2u;  // 0..48 even
    const float* bp = (const float*)Bi + sig * 10400u + q * 2600u + m1l * 104u;
    float cthA, sthA, cthB, sthB;
    __sincosf(PI2 * (float)m2 * 0.01f, &sthA, &cthA);
    __sincosf(PI2 * (float)(m2 + 1u) * 0.01f, &sthB, &cthB);
    float cA = 1.0f, sA = 0.0f, cB = 1.0f, sB = 0.0f;
    float r0e = 0.f, r0o = 0.f, r1e = 0.f, r1o = 0.f;
#pragma unroll 4
    for (int jj = 0; jj < 26; ++jj) {
      const float4 v0 = *(const float4*)(bp + 4 * jj);
      r0e += v0.x * cA - v0.y * sA;      // n2 even
      r1e += v0.x * cB - v0.y * sB;
      float cA1 = cA * cthA - sA * sthA, sA1 = sA * cthA + cA * sthA;
      float cB1 = cB * cthB - sB * sthB, sB1 = sB * cthB + cB * sthB;
      r0o += v0.z * cA1 - v0.w * sA1;    // n2 odd
      r1o += v0.z * cB1 - v0.w * sB1;
      cA = cA1 * cthA - sA1 * sthA; sA = sA1 * cthA + cA1 * sthA;
      cB = cB1 * cthB - sB1 * sthB; sB = sB1 * cthB + cB1 * sthB;
    }
    ls[m2 * 26 + m1l]          = (r0e + r0o) * 2e-4f;
    ls[(m2 + 1u) * 26 + m1l]   = (r1e + r1o) * 2e-4f;
    ls[(m2 + 50u) * 26 + m1l]  = (r0e - r0o) * 2e-4f;
    ls[(m2 + 51u) * 26 + m1l]  = (r1e - r1o) * 2e-4f;
  }
  __syncthreads();
  float* mp = mol + sig * 10000u + q * 25u;
  for (int i = tid; i < 2500; i += 640) {
    int m2 = i / 25, m1l = i % 25;
    mp[100 * m2 + m1l] = ls[m2 * 26 + m1l];
  }
}

// ---------------- projection: float4 compute (1 spread + 2 broadcast b128 per dl) ----------------
__global__ __launch_bounds__(512) void k_proj(const float* __restrict__ mol,
                                              const float* __restrict__ W,
                                              float* __restrict__ part) {
  __shared__ float molS[40 * 68];      // [dl][b], pad 68 (16B-aligned rows)
  __shared__ float WS[40][260];        // [dl][p], pad 260 (16B-aligned rows)
  int tid = threadIdx.x;
  int d0 = blockIdx.x * 40;
  for (int i = tid; i < 40 * 64; i += 512) {
    int b = i / 40, dl = i % 40;
    molS[dl * 68 + b] = mol[(size_t)b * 10000 + d0 + dl];
  }
  for (int i = tid; i < 40 * 256; i += 512) {
    int p = i / 40, dl = i % 40;
    WS[dl][p] = W[(size_t)p * 10000 + d0 + dl];
  }
  __syncthreads();
  int p0 = (tid & 63) * 4;
  int bh = (tid >> 6) * 8;
  float acc[4][8] = {};
#pragma unroll 4
  for (int dl = 0; dl < 40; ++dl) {
    const float4 wv = *(const float4*)(&WS[dl][p0]);
    const float4 m0 = *(const float4*)(molS + dl * 68 + bh);
    const float4 m1 = *(const float4*)(molS + dl * 68 + bh + 4);
#pragma unroll
    for (int j = 0; j < 4; ++j) {
      float w = (j == 0) ? wv.x : (j == 1) ? wv.y : (j == 2) ? wv.z : wv.w;
      acc[j][0] += w * m0.x;  acc[j][1] += w * m0.y;
      acc[j][2] += w * m0.z;  acc[j][3] += w * m0.w;
      acc[j][4] += w * m1.x;  acc[j][5] += w * m1.y;
      acc[j][6] += w * m1.z;  acc[j][7] += w * m1.w;
    }
  }
#pragma unroll
  for (int b = 0; b < 8; ++b) {
    float4 v = make_float4(acc[0][b], acc[1][b], acc[2][b], acc[3][b]);
    *(float4*)(part + (size_t)blockIdx.x * 16384 + (bh + b) * 256 + p0) = v;
  }
}

// ---------------- reduce partials + bias ----------------
__global__ __launch_bounds__(256) void k_red(const float* __restrict__ part,
                                             const float* __restrict__ bias,
                                             float* __restrict__ out) {
  __shared__ float red[4][64];
  int tid = threadIdx.x;
  int pl = tid & 63, cg = tid >> 6;
  int b = blockIdx.x;
  int p = blockIdx.y * 64 + pl;
  float acc = 0.0f;
#pragma unroll 8
  for (int ch = cg; ch < 250; ch += 4)
    acc += part[(size_t)ch * 16384 + b * 256 + p];
  red[cg][pl] = acc;
  __syncthreads();
  if (tid < 64)
    out[b * 256 + p] = red[0][pl] + red[1][pl] + red[2][pl] + red[3][pl] + bias[p];
}

extern "C" void kernel_launch(void* const* d_in, const int* in_sizes, int n_in,
                              void* d_out, int out_size, void* d_ws, size_t ws_size,
                              hipStream_t stream) {
  const float* atom  = (const float*)d_in[0];   // [10,10000]
  const float* pos   = (const float*)d_in[1];   // [128,10000]
  const float* clo   = (const float*)d_in[2];   // [10000]
  const float* W     = (const float*)d_in[3];   // [256,10000]
  const float* bias  = (const float*)d_in[4];   // [256]
  const float* tmask = (const float*)d_in[5];   // [64,128]
  const float* rmask = (const float*)d_in[6];   // [64,8]
  const int*   aidx  = (const int*)d_in[7];     // [64,128]
  const int*   rpos  = (const int*)d_in[8];     // [64,8,2]
  float* out = (float*)d_out;                   // [64,256]

  char* ws = (char*)d_ws;
  size_t off = 0;
  auto alloc = [&](size_t n) { off = (off + 255) & ~(size_t)255; size_t o = off; off += n; return o; };
  char* regA   = ws + alloc(16777216);          // Bi (2.66MB) / partials (16.4MB)
  float2* Bi   = (float2*)regA;                 // i1/i2 use Bi before proj writes part
  float*  part = (float*)regA;
  float2* spec = (float2*)(ws + alloc((size_t)NSIG * FS * 8));
  float2* G    = (float2*)(ws + alloc((size_t)64 * 10000 * 8));
  float*  mol  = (float*)(ws + alloc((size_t)64 * 10000 * 4));

  k_fwd<<<dim3(NSIG, 3), dim3(512), 0, stream>>>(atom, pos, clo, spec);
  k_mix<<<dim3(80, 4), dim3(256), 0, stream>>>(spec, tmask, rmask, aidx, rpos, G);
  k_i1<<<dim3(64, 3), dim3(512), 0, stream>>>(G, Bi);
  k_i2<<<dim3(64, 4), dim3(640), 0, stream>>>(Bi, mol);
  k_proj<<<dim3(250), dim3(512), 0, stream>>>(mol, W, part);
  k_red<<<dim3(64, 4), dim3(256), 0, stream>>>(part, bias, out);
}

// Round 8
// 155.956 us; speedup vs baseline: 1.2250x; 1.0004x over previous
//
#include <hip/hip_runtime.h>

#define PI2 6.28318530717958647692f

// D = 10000 = 100 x 100; F = 5001; signals: 128 pos + 10 atom + 1 closure = 139
#define NSIG 139
#define FS   5120      // spectrum row stride (float2)

// ---------------- fused forward (f1+f2), Hermitian-paired, radix-4 folded ----------------
// 51 = 3 x 17: grid (139,3), 512 threads, nk1=17 -> fold computed 3x/sig instead of 6x,
// no near-empty tail block, ntile1=425 single uniform round.
__global__ __launch_bounds__(512) void k_fwd(
                     const float* __restrict__ atom, const float* __restrict__ pos,
                     const float* __restrict__ clo, float2* __restrict__ spec) {
  __shared__ float lds[13600];   // 54.4 KB union: phase1 tables (10000) / xs(6800)+cse/cso(6800)
  unsigned sig = blockIdx.x, q = blockIdx.y;
  unsigned k1base = q * 17u;
  unsigned nk1 = 17u;
  const float* xb = (sig < 128u) ? (pos + sig * 10000u)
                   : ((sig < 138u) ? (atom + (sig - 128u) * 10000u) : clo);
  int tid = threadIdx.x;

  // ---- phase 1a: radix-4 fold of x ----
  {
    float* csA = lds;
    float* csB = lds + 2500;
    float* csG = lds + 5000;
    float* csH = lds + 7500;
    for (int t2 = tid; t2 < 625; t2 += 512) {
      const float* p = xb + (t2 / 25) * 100 + (t2 % 25) * 4;
      float4 x0 = *(const float4*)(p);
      float4 x1 = *(const float4*)(p + 2500);
      float4 x2 = *(const float4*)(p + 5000);
      float4 x3 = *(const float4*)(p + 7500);
      float4 A, B, G, H;
      A.x = (x0.x + x2.x) + (x1.x + x3.x);
      A.y = (x0.y + x2.y) + (x1.y + x3.y);
      A.z = (x0.z + x2.z) + (x1.z + x3.z);
      A.w = (x0.w + x2.w) + (x1.w + x3.w);
      B.x = (x0.x + x2.x) - (x1.x + x3.x);
      B.y = (x0.y + x2.y) - (x1.y + x3.y);
      B.z = (x0.z + x2.z) - (x1.z + x3.z);
      B.w = (x0.w + x2.w) - (x1.w + x3.w);
      G.x = x0.x - x2.x;  G.y = x0.y - x2.y;
      G.z = x0.z - x2.z;  G.w = x0.w - x2.w;
      H.x = x1.x - x3.x;  H.y = x1.y - x3.y;
      H.z = x1.z - x3.z;  H.w = x1.w - x3.w;
      *(float4*)(csA + t2 * 4) = A;
      *(float4*)(csB + t2 * 4) = B;
      *(float4*)(csG + t2 * 4) = G;
      *(float4*)(csH + t2 * 4) = H;
    }
  }
  __syncthreads();

  // ---- phase 1b: 25-iter folded DFT + phase-2 twiddles ----
  unsigned ntile1 = nk1 * 25u;   // 425
  unsigned k1l = tid / 25u, n2q = (unsigned)tid % 25u, n2 = n2q * 4u;
  bool have = (unsigned)tid < ntile1;
  unsigned k1 = k1base + k1l;
  float resA[8], resB[8];
  if (have) {
    float cth, sth;
    __sincosf(PI2 * (float)k1 * 0.01f, &sth, &cth);
    unsigned m = k1 & 3u;
    const float4* creP = (const float4*)((m == 0u) ? lds
                          : (m == 2u) ? (lds + 2500) : (lds + 5000)) + n2q;
    const float4* cimP = (const float4*)(lds + 7500) + n2q;
    float im_mul = (m == 1u) ? 1.0f : (m == 3u) ? -1.0f : 0.0f;
    float c = 1.0f, s = 0.0f;
    float ar[4] = {}, as[4] = {};
#pragma unroll 5
    for (int n1l = 0; n1l < 25; ++n1l) {
      float4 Cre = creP[n1l * 25];
      float4 Cim = cimP[n1l * 25];
      float se = im_mul * s, ce = im_mul * c;
      ar[0] += Cre.x * c - Cim.x * se;  as[0] += Cim.x * ce + Cre.x * s;
      ar[1] += Cre.y * c - Cim.y * se;  as[1] += Cim.y * ce + Cre.y * s;
      ar[2] += Cre.z * c - Cim.z * se;  as[2] += Cim.z * ce + Cre.z * s;
      ar[3] += Cre.w * c - Cim.w * se;  as[3] += Cim.w * ce + Cre.w * s;
      float cn = c * cth - s * sth;
      float sn = s * cth + c * sth;
      c = cn; s = sn;
    }
    unsigned rb = (100u - k1) % 100u;
#pragma unroll
    for (int j = 0; j < 4; ++j) {
      float swA, cwA, swB, cwB;
      __sincosf(PI2 * (float)((n2 + j) * k1) * 1e-4f, &swA, &cwA);
      __sincosf(PI2 * (float)((n2 + j) * rb) * 1e-4f, &swB, &cwB);
      resA[2 * j + 0] = ar[j] * cwA - as[j] * swA;
      resA[2 * j + 1] = -(as[j] * cwA + ar[j] * swA);
      resB[2 * j + 0] = ar[j] * cwB + as[j] * swB;
      resB[2 * j + 1] = as[j] * cwB - ar[j] * swB;
    }
  }
  __syncthreads();   // phase-1 tables dead; lds reused as xs below
  float* xs = lds;   // nrow x 200 floats (34 x 200 = 6800)
  if (have) {
    float* pA = xs + k1l * 200u + n2 * 2u;
    float* pB = xs + (nk1 + k1l) * 200u + n2 * 2u;
    *(float4*)(pA + 0) = make_float4(resA[0], resA[1], resA[2], resA[3]);
    *(float4*)(pA + 4) = make_float4(resA[4], resA[5], resA[6], resA[7]);
    *(float4*)(pB + 0) = make_float4(resB[0], resB[1], resB[2], resB[3]);
    *(float4*)(pB + 4) = make_float4(resB[4], resB[5], resB[6], resB[7]);
  }
  __syncthreads();

  // ---- phase 3a: radix-4 fold of the complex rows (e^{-i} direction) ----
  unsigned nrow = 2u * nk1;      // 34
  float* cse = lds + 6800;
  float* cso = lds + 10200;
  for (int t3 = tid; t3 < (int)(nrow * 25u); t3 += 512) {
    const float* br = xs + (t3 / 25) * 200;
    int n2l = t3 % 25;
    float2 b0 = *(const float2*)(br + 2 * n2l);
    float2 b1 = *(const float2*)(br + 2 * (25 + n2l));
    float2 b2 = *(const float2*)(br + 2 * (50 + n2l));
    float2 b3 = *(const float2*)(br + 2 * (75 + n2l));
    float4 e, o;
    e.x = (b0.x + b2.x) + (b1.x + b3.x);
    e.y = (b0.y + b2.y) + (b1.y + b3.y);
    e.z = (b0.x + b2.x) - (b1.x + b3.x);
    e.w = (b0.y + b2.y) - (b1.y + b3.y);
    o.x = b0.x - b2.x;   // P
    o.y = b1.y - b3.y;   // Q
    o.z = b0.y - b2.y;   // R
    o.w = b1.x - b3.x;   // T
    *(float4*)(cse + t3 * 4) = e;
    *(float4*)(cso + t3 * 4) = o;
  }
  __syncthreads();

  // ---- phase 3b: 25 uniform k2-pairs (k2 <= 48); stores unconditional ----
  unsigned ntile3 = nrow * 25u;  // 850
  for (unsigned t = tid; t < ntile3; t += 512u) {
    unsigned lr = t / 25u, k2 = (t % 25u) * 2u;
    unsigned gk1 = (lr < nk1) ? (k1base + lr) : ((100u - (k1base + (lr - nk1))) % 100u);
    float cthA, sthA, cthB, sthB;
    __sincosf(PI2 * (float)k2 * 0.01f, &sthA, &cthA);
    __sincosf(PI2 * (float)(k2 + 1) * 0.01f, &sthB, &cthB);
    bool hi = (k2 & 2u) != 0u;
    float sq = hi ? -1.0f : 1.0f;
    const float4* pe = (const float4*)(cse + lr * 100);
    const float4* po = (const float4*)(cso + lr * 100);
    float cA = 1.0f, sA = 0.0f, cB = 1.0f, sB = 0.0f;
    float reA = 0.f, imA = 0.f, reB = 0.f, imB = 0.f;
#pragma unroll 5
    for (int n2l = 0; n2l < 25; ++n2l) {
      float4 e = pe[n2l];
      float4 o = po[n2l];
      float car = hi ? e.z : e.x;
      float cai = hi ? e.w : e.y;
      float cbr = o.x + sq * o.y;
      float cbi = o.z - sq * o.w;
      reA += car * cA + cai * sA;  imA += cai * cA - car * sA;
      reB += cbr * cB + cbi * sB;  imB += cbi * cB - cbr * sB;
      float cA1 = cA * cthA - sA * sthA, sA1 = sA * cthA + cA * sthA;
      float cB1 = cB * cthB - sB * sthB, sB1 = sB * cthB + cB * sthB;
      cA = cA1; sA = sA1; cB = cB1; sB = sB1;
    }
    unsigned kA = gk1 + 100u * k2;
    spec[sig * FS + kA] = make_float2(reA, imA);
    spec[sig * FS + kA + 100u] = make_float2(reB, imB);
  }
  // k2 = 50: only gk1 = 0 survives (kA = 5000); hi=true table, twiddle (-1)^n2l
  if (k1base == 0u && tid == 255) {
    const float4* pe = (const float4*)(cse);   // lr = 0 (gk1 = 0)
    float c = 1.0f, re = 0.f, im = 0.f;
#pragma unroll 5
    for (int n2l = 0; n2l < 25; ++n2l) {
      float4 e = pe[n2l];
      re += e.z * c; im += e.w * c;
      c = -c;
    }
    spec[sig * FS + 5000u] = make_float2(re, im);
  }
}

// ---------------- mix: b-tile 16, k-chunk 32, 8-way s-split; grid (157,4) = 628 blocks ----------------
// Same total VALU as k64/4-split, but 52 KB LDS -> 3 blocks/CU and 628 blocks -> balanced
// makespan (~1.5 T64-units vs 2.0 with 320 blocks @ 2/CU).
__global__ __launch_bounds__(256) void k_mix(const float2* __restrict__ spec,
                      const float* __restrict__ tmask, const float* __restrict__ rmask,
                      const int* __restrict__ aidx, const int* __restrict__ rpos,
                      float2* __restrict__ G) {
  __shared__ float2 FaS[10][32];       // 2560 B
  __shared__ float tmS[128][16];       // 8192 B
  __shared__ int   aiS[128][16];       // 8192 B
  __shared__ float rmS[16][8];         // 512 B
  __shared__ int   rpS[16][8][2];      // 1024 B
  __shared__ float2 red[8][16][32];    // 32768 B  (total 53248 B = 52 KB)
  int tid = threadIdx.x;
  int kl = tid & 31, grp = tid >> 5;   // 8 groups of 32 lanes
  int k = blockIdx.x * 32 + kl;
  int kc = k > 5000 ? 5000 : k;
  int b0 = blockIdx.y * 16;
  for (int i = tid; i < 320; i += 256) {
    int a = i >> 5, kk = i & 31;
    int kg = blockIdx.x * 32 + kk; if (kg > 5000) kg = 5000;
    FaS[a][kk] = spec[(128 + a) * FS + kg];
  }
  for (int i = tid; i < 16 * 128; i += 256) {
    int bb = i >> 7, ss = i & 127;
    tmS[ss][bb] = tmask[(b0 + bb) * 128 + ss];
    aiS[ss][bb] = aidx[(b0 + bb) * 128 + ss];
  }
  if (tid < 128) {
    int bb = tid >> 3, rr = tid & 7;
    rmS[bb][rr] = rmask[(b0 + bb) * 8 + rr];
    rpS[bb][rr][0] = rpos[((b0 + bb) * 8 + rr) * 2 + 0];
    rpS[bb][rr][1] = rpos[((b0 + bb) * 8 + rr) * 2 + 1];
  }
  __syncthreads();
  float fr[16] = {}, fi[16] = {};
  int sbase = grp * 16;
#pragma unroll 2
  for (int si = 0; si < 16; ++si) {
    int s = sbase + si;
    float2 fp = spec[s * FS + kc];
#pragma unroll
    for (int bq = 0; bq < 4; ++bq) {
      const int4  ai4 = *(const int4*)(&aiS[s][bq * 4]);
      const float4 tm4 = *(const float4*)(&tmS[s][bq * 4]);
#pragma unroll
      for (int bj = 0; bj < 4; ++bj) {
        int b = bq * 4 + bj;
        int a = (bj == 0) ? ai4.x : (bj == 1) ? ai4.y : (bj == 2) ? ai4.z : ai4.w;
        float tm = (bj == 0) ? tm4.x : (bj == 1) ? tm4.y : (bj == 2) ? tm4.z : tm4.w;
        float2 fa = FaS[a][kl];
        fr[b] += tm * (fa.x * fp.x - fa.y * fp.y);
        fi[b] += tm * (fa.x * fp.y + fa.y * fp.x);
      }
    }
  }
  // ring: each group handles one r (8 groups = 8 rings)
  {
    float2 fc = spec[138 * FS + kc];
    int r = grp;
#pragma unroll
    for (int b = 0; b < 16; ++b) {
      int p0 = rpS[b][r][0], p1 = rpS[b][r][1];
      float rm = rmS[b][r];
      float2 f0 = spec[p0 * FS + kc];
      float2 f1 = spec[p1 * FS + kc];
      float tr = f0.x * f1.x - f0.y * f1.y;
      float ti = f0.x * f1.y + f0.y * f1.x;
      fr[b] += rm * (tr * fc.x - ti * fc.y);
      fi[b] += rm * (tr * fc.y + ti * fc.x);
    }
  }
#pragma unroll
  for (int b = 0; b < 16; ++b) red[grp][b][kl] = make_float2(fr[b], fi[b]);
  __syncthreads();
#pragma unroll
  for (int j = 0; j < 2; ++j) {
    int slot = j * 256 + tid;
    int b = slot >> 5, kk = slot & 31;
    int kg = blockIdx.x * 32 + kk;
    if (kg <= 5000) {
      float R = red[0][b][kk].x + red[1][b][kk].x + red[2][b][kk].x + red[3][b][kk].x
              + red[4][b][kk].x + red[5][b][kk].x + red[6][b][kk].x + red[7][b][kk].x;
      float I = red[0][b][kk].y + red[1][b][kk].y + red[2][b][kk].y + red[3][b][kk].y
              + red[4][b][kk].y + red[5][b][kk].y + red[6][b][kk].y + red[7][b][kk].y;
      if (kg == 0 || kg == 5000) I = 0.0f;   // exact Hermitian guard
      G[(size_t)(b0 + b) * 10000 + kg] = make_float2(R, I);
      if (kg >= 1 && kg <= 4999)
        G[(size_t)(b0 + b) * 10000 + (10000 - kg)] = make_float2(R, -I);
    }
  }
}

// ---------------- inverse stage 1: radix-4 folded + (m1, m1+50) pairing; grid (64,3) x 512 ----------------
__global__ __launch_bounds__(512) void k_i1(const float2* __restrict__ G,
                                            float2* __restrict__ Bi) {
  __shared__ float lds[10400];   // 4 tables x [25][26] float4 = 41.6 KB
  unsigned sig = blockIdx.x;
  const float* gp = (const float*)(G + sig * 10000u);
  int tid = threadIdx.x;
  float* c0v = lds;          // {C0.re(n2), C0.im(n2), C0.re(n2+1), C0.im(n2+1)}
  float* c2v = lds + 2600;
  float* cpr = lds + 5200;   // {P, R, P', R'}
  float* cqt = lds + 7800;   // {Q, T, Q', T'}
  for (int t2 = tid; t2 < 650; t2 += 512) {
    const float* p = gp + (t2 / 26) * 200 + (t2 % 26) * 4;
    float4 g0 = *(const float4*)(p);
    float4 g1 = *(const float4*)(p + 5000);
    float4 g2 = *(const float4*)(p + 10000);
    float4 g3 = *(const float4*)(p + 15000);
    float4 a, b, pr, qt;
    a.x = (g0.x + g2.x) + (g1.x + g3.x);
    a.y = (g0.y + g2.y) + (g1.y + g3.y);
    a.z = (g0.z + g2.z) + (g1.z + g3.z);
    a.w = (g0.w + g2.w) + (g1.w + g3.w);
    b.x = (g0.x + g2.x) - (g1.x + g3.x);
    b.y = (g0.y + g2.y) - (g1.y + g3.y);
    b.z = (g0.z + g2.z) - (g1.z + g3.z);
    b.w = (g0.w + g2.w) - (g1.w + g3.w);
    pr.x = g0.x - g2.x;  pr.y = g0.y - g2.y;
    pr.z = g0.z - g2.z;  pr.w = g0.w - g2.w;
    qt.x = g1.y - g3.y;  qt.y = g1.x - g3.x;
    qt.z = g1.w - g3.w;  qt.w = g1.z - g3.z;
    *(float4*)(c0v + t2 * 4) = a;
    *(float4*)(c2v + t2 * 4) = b;
    *(float4*)(cpr + t2 * 4) = pr;
    *(float4*)(cqt + t2 * 4) = qt;
  }
  __syncthreads();
  unsigned t = blockIdx.y * 512u + tid;
  if (t >= 1300u) return;
  unsigned m1 = t / 26u, n2p = t % 26u, n2 = n2p * 2u;   // m1 in [0,50)
  float cth, sth;
  __sincosf(PI2 * (float)m1 * 0.01f, &sth, &cth);
  unsigned m = m1 & 3u;
  const float4* pe  = (const float4*)((m == 0u) ? c0v : (m == 2u) ? c2v : cpr) + n2p;
  const float4* pe2 = (const float4*)((m == 0u) ? c2v : (m == 2u) ? c0v : cpr) + n2p;
  const float4* pq  = (const float4*)cqt + n2p;
  float qmul = (m == 1u) ? -1.0f : (m == 3u) ? 1.0f : 0.0f;
  float qmul2 = -qmul;
  float c = 1.0f, s = 0.0f, sg = 1.0f;
  float reA = 0.f, imA = 0.f, reB = 0.f, imB = 0.f;
  float reA2 = 0.f, imA2 = 0.f, reB2 = 0.f, imB2 = 0.f;
#pragma unroll 5
  for (int n1l = 0; n1l < 25; ++n1l) {
    float4 ev = pe[n1l * 26];
    float4 e2 = pe2[n1l * 26];
    float4 qv = pq[n1l * 26];
    float gx = ev.x + qmul * qv.x,  gy = ev.y - qmul * qv.y;
    float gz = ev.z + qmul * qv.z,  gw = ev.w - qmul * qv.w;
    float hx = e2.x + qmul2 * qv.x, hy = e2.y - qmul2 * qv.y;
    float hz = e2.z + qmul2 * qv.z, hw = e2.w - qmul2 * qv.w;
    reA += gx * c - gy * s;  imA += gy * c + gx * s;
    reB += gz * c - gw * s;  imB += gw * c + gz * s;
    float cs = sg * c, ss = sg * s;
    reA2 += hx * cs - hy * ss;  imA2 += hy * cs + hx * ss;
    reB2 += hz * cs - hw * ss;  imB2 += hw * cs + hz * ss;
    float cn = c * cth - s * sth;
    float sn = s * cth + c * sth;
    c = cn; s = sn; sg = -sg;
  }
  float w0 = (n2 == 0u || n2 == 50u) ? 0.5f : 1.0f;
  float w1 = (n2 == 50u) ? 0.0f : 1.0f;   // col 51 unused
  {
    float sw0, cw0, sw1, cw1;
    __sincosf(PI2 * (float)(n2 * m1) * 1e-4f, &sw0, &cw0);
    __sincosf(PI2 * (float)((n2 + 1u) * m1) * 1e-4f, &sw1, &cw1);
    float4 outv;
    outv.x = (reA * cw0 - imA * sw0) * w0;
    outv.y = (imA * cw0 + reA * sw0) * w0;
    outv.z = (reB * cw1 - imB * sw1) * w1;
    outv.w = (imB * cw1 + reB * sw1) * w1;
    *(float4*)((float*)Bi + (sig * 5200u + m1 * 52u + n2) * 2) = outv;
  }
  {
    unsigned m1b = m1 + 50u;
    float sw0, cw0, sw1, cw1;
    __sincosf(PI2 * (float)(n2 * m1b) * 1e-4f, &sw0, &cw0);
    __sincosf(PI2 * (float)((n2 + 1u) * m1b) * 1e-4f, &sw1, &cw1);
    float4 outv;
    outv.x = (reA2 * cw0 - imA2 * sw0) * w0;
    outv.y = (imA2 * cw0 + reA2 * sw0) * w0;
    outv.z = (reB2 * cw1 - imB2 * sw1) * w1;
    outv.w = (imB2 * cw1 + reB2 * sw1) * w1;
    *(float4*)((float*)Bi + (sig * 5200u + m1b * 52u + n2) * 2) = outv;
  }
}

// ---------------- inverse stage 2: (m2, m2+50) pairing, LDS-transposed coalesced mol write ----------------
__global__ __launch_bounds__(640) void k_i2(const float2* __restrict__ Bi,
                                            float* __restrict__ mol) {
  __shared__ float ls[100 * 26];   // [m2][m1l] padded-26 (10.4 KB)
  unsigned sig = blockIdx.x, q = blockIdx.y;
  int tid = threadIdx.x;
  if (tid < 625) {
    unsigned m1l = (unsigned)tid / 25u;   // 0..24
    unsigned m2 = ((unsigned)tid % 25u) * 2u;  // 0..48 even
    const float* bp = (const float*)Bi + sig * 10400u + q * 2600u + m1l * 104u;
    float cthA, sthA, cthB, sthB;
    __sincosf(PI2 * (float)m2 * 0.01f, &sthA, &cthA);
    __sincosf(PI2 * (float)(m2 + 1u) * 0.01f, &sthB, &cthB);
    float cA = 1.0f, sA = 0.0f, cB = 1.0f, sB = 0.0f;
    float r0e = 0.f, r0o = 0.f, r1e = 0.f, r1o = 0.f;
#pragma unroll 4
    for (int jj = 0; jj < 26; ++jj) {
      const float4 v0 = *(const float4*)(bp + 4 * jj);
      r0e += v0.x * cA - v0.y * sA;      // n2 even
      r1e += v0.x * cB - v0.y * sB;
      float cA1 = cA * cthA - sA * sthA, sA1 = sA * cthA + cA * sthA;
      float cB1 = cB * cthB - sB * sthB, sB1 = sB * cthB + cB * sthB;
      r0o += v0.z * cA1 - v0.w * sA1;    // n2 odd
      r1o += v0.z * cB1 - v0.w * sB1;
      cA = cA1 * cthA - sA1 * sthA; sA = sA1 * cthA + cA1 * sthA;
      cB = cB1 * cthB - sB1 * sthB; sB = sB1 * cthB + cB1 * sthB;
    }
    ls[m2 * 26 + m1l]          = (r0e + r0o) * 2e-4f;
    ls[(m2 + 1u) * 26 + m1l]   = (r1e + r1o) * 2e-4f;
    ls[(m2 + 50u) * 26 + m1l]  = (r0e - r0o) * 2e-4f;
    ls[(m2 + 51u) * 26 + m1l]  = (r1e - r1o) * 2e-4f;
  }
  __syncthreads();
  float* mp = mol + sig * 10000u + q * 25u;
  for (int i = tid; i < 2500; i += 640) {
    int m2 = i / 25, m1l = i % 25;
    mp[100 * m2 + m1l] = ls[m2 * 26 + m1l];
  }
}

// ---------------- projection: float4 compute (1 spread + 2 broadcast b128 per dl) ----------------
__global__ __launch_bounds__(512) void k_proj(const float* __restrict__ mol,
                                              const float* __restrict__ W,
                                              float* __restrict__ part) {
  __shared__ float molS[40 * 68];      // [dl][b], pad 68 (16B-aligned rows)
  __shared__ float WS[40][260];        // [dl][p], pad 260 (16B-aligned rows)
  int tid = threadIdx.x;
  int d0 = blockIdx.x * 40;
  for (int i = tid; i < 40 * 64; i += 512) {
    int b = i / 40, dl = i % 40;
    molS[dl * 68 + b] = mol[(size_t)b * 10000 + d0 + dl];
  }
  for (int i = tid; i < 40 * 256; i += 512) {
    int p = i / 40, dl = i % 40;
    WS[dl][p] = W[(size_t)p * 10000 + d0 + dl];
  }
  __syncthreads();
  int p0 = (tid & 63) * 4;
  int bh = (tid >> 6) * 8;
  float acc[4][8] = {};
#pragma unroll 4
  for (int dl = 0; dl < 40; ++dl) {
    const float4 wv = *(const float4*)(&WS[dl][p0]);
    const float4 m0 = *(const float4*)(molS + dl * 68 + bh);
    const float4 m1 = *(const float4*)(molS + dl * 68 + bh + 4);
#pragma unroll
    for (int j = 0; j < 4; ++j) {
      float w = (j == 0) ? wv.x : (j == 1) ? wv.y : (j == 2) ? wv.z : wv.w;
      acc[j][0] += w * m0.x;  acc[j][1] += w * m0.y;
      acc[j][2] += w * m0.z;  acc[j][3] += w * m0.w;
      acc[j][4] += w * m1.x;  acc[j][5] += w * m1.y;
      acc[j][6] += w * m1.z;  acc[j][7] += w * m1.w;
    }
  }
#pragma unroll
  for (int b = 0; b < 8; ++b) {
    float4 v = make_float4(acc[0][b], acc[1][b], acc[2][b], acc[3][b]);
    *(float4*)(part + (size_t)blockIdx.x * 16384 + (bh + b) * 256 + p0) = v;
  }
}

// ---------------- reduce partials + bias ----------------
__global__ __launch_bounds__(256) void k_red(const float* __restrict__ part,
                                             const float* __restrict__ bias,
                                             float* __restrict__ out) {
  __shared__ float red[4][64];
  int tid = threadIdx.x;
  int pl = tid & 63, cg = tid >> 6;
  int b = blockIdx.x;
  int p = blockIdx.y * 64 + pl;
  float acc = 0.0f;
#pragma unroll 8
  for (int ch = cg; ch < 250; ch += 4)
    acc += part[(size_t)ch * 16384 + b * 256 + p];
  red[cg][pl] = acc;
  __syncthreads();
  if (tid < 64)
    out[b * 256 + p] = red[0][pl] + red[1][pl] + red[2][pl] + red[3][pl] + bias[p];
}

extern "C" void kernel_launch(void* const* d_in, const int* in_sizes, int n_in,
                              void* d_out, int out_size, void* d_ws, size_t ws_size,
                              hipStream_t stream) {
  const float* atom  = (const float*)d_in[0];   // [10,10000]
  const float* pos   = (const float*)d_in[1];   // [128,10000]
  const float* clo   = (const float*)d_in[2];   // [10000]
  const float* W     = (const float*)d_in[3];   // [256,10000]
  const float* bias  = (const float*)d_in[4];   // [256]
  const float* tmask = (const float*)d_in[5];   // [64,128]
  const float* rmask = (const float*)d_in[6];   // [64,8]
  const int*   aidx  = (const int*)d_in[7];     // [64,128]
  const int*   rpos  = (const int*)d_in[8];     // [64,8,2]
  float* out = (float*)d_out;                   // [64,256]

  char* ws = (char*)d_ws;
  size_t off = 0;
  auto alloc = [&](size_t n) { off = (off + 255) & ~(size_t)255; size_t o = off; off += n; return o; };
  char* regA   = ws + alloc(16777216);          // Bi (2.66MB) / partials (16.4MB)
  float2* Bi   = (float2*)regA;                 // i1/i2 use Bi before proj writes part
  float*  part = (float*)regA;
  float2* spec = (float2*)(ws + alloc((size_t)NSIG * FS * 8));
  float2* G    = (float2*)(ws + alloc((size_t)64 * 10000 * 8));
  float*  mol  = (float*)(ws + alloc((size_t)64 * 10000 * 4));

  k_fwd<<<dim3(NSIG, 3), dim3(512), 0, stream>>>(atom, pos, clo, spec);
  k_mix<<<dim3(157, 4), dim3(256), 0, stream>>>(spec, tmask, rmask, aidx, rpos, G);
  k_i1<<<dim3(64, 3), dim3(512), 0, stream>>>(G, Bi);
  k_i2<<<dim3(64, 4), dim3(640), 0, stream>>>(Bi, mol);
  k_proj<<<dim3(250), dim3(512), 0, stream>>>(mol, W, part);
  k_red<<<dim3(64, 4), dim3(256), 0, stream>>>(part, bias, out);
}